// Round 1
// baseline (751.614 us; speedup 1.0000x reference)
//
#include <hip/hip_runtime.h>
#include <math.h>

#define N_NODES 40000
#define N_EDGES 640000
#define HIDDEN 128
#define N_LAYERS 4
#define N_CLASSES 40
#define SCALING 0.08838834764831845f

// ---------------- CSR build: row_start[i] = lower_bound(dst, i) ----------------
__global__ void build_csr(const int* __restrict__ dst, int* __restrict__ row_start) {
  int i = blockIdx.x * blockDim.x + threadIdx.x;
  if (i > N_NODES) return;
  int lo = 0, hi = N_EDGES;
  while (lo < hi) {
    int mid = (lo + hi) >> 1;
    if (dst[mid] < i) lo = mid + 1; else hi = mid;
  }
  row_start[i] = lo;
}

// ---------------- QKV GEMM: C = A(40000x128) @ W(128x128) + b, times scale -----
// grid.x = 625 (64 rows each), grid.y = 3 (q,k,v). 256 threads.
__global__ __launch_bounds__(256, 1) void gemm_qkv(
    const float* __restrict__ A,
    const float* __restrict__ Wq, const float* __restrict__ Wk, const float* __restrict__ Wv,
    const float* __restrict__ bq, const float* __restrict__ bk, const float* __restrict__ bv,
    float* __restrict__ q, float* __restrict__ k, float* __restrict__ v)
{
  __shared__ float Ws[64][128];   // 32 KB: K-chunk of W
  __shared__ float As[64][68];    // 17.4 KB: padded A tile (68 = 64+4 pad)

  const float* W; const float* bias; float* C; float scale;
  if (blockIdx.y == 0)      { W = Wq; bias = bq; C = q; scale = SCALING; }
  else if (blockIdx.y == 1) { W = Wk; bias = bk; C = k; scale = 1.0f; }
  else                      { W = Wv; bias = bv; C = v; scale = 1.0f; }

  const int t = threadIdx.x;
  const int base = blockIdx.x * 64;
  const int tx = t & 15, ty = t >> 4;
  const int c0 = tx * 4, c1 = tx * 4 + 64;

  float4 acc0[4] = {};
  float4 acc1[4] = {};

  for (int kc = 0; kc < 128; kc += 64) {
    __syncthreads();
    // load W chunk rows [kc, kc+64): 2048 float4, 8 per thread
    {
      const float4* W4 = (const float4*)(W + (size_t)kc * 128);
      #pragma unroll
      for (int i2 = 0; i2 < 8; ++i2) {
        int idx = t + 256 * i2;
        int kr = idx >> 5, c4 = idx & 31;
        *(float4*)&Ws[kr][c4 * 4] = W4[idx];
      }
    }
    // load A tile cols [kc, kc+64): 1024 float4, 4 per thread
    {
      #pragma unroll
      for (int i2 = 0; i2 < 4; ++i2) {
        int idx = t + 256 * i2;
        int r = idx >> 4, c4 = idx & 15;
        *(float4*)&As[r][c4 * 4] =
            *(const float4*)(A + (size_t)(base + r) * 128 + kc + c4 * 4);
      }
    }
    __syncthreads();

    #pragma unroll 2
    for (int kk = 0; kk < 64; kk += 4) {
      float4 a[4];
      #pragma unroll
      for (int j = 0; j < 4; ++j) a[j] = *(const float4*)&As[ty * 4 + j][kk];
      #pragma unroll
      for (int u = 0; u < 4; ++u) {
        float4 w0 = *(const float4*)&Ws[kk + u][c0];
        float4 w1 = *(const float4*)&Ws[kk + u][c1];
        #pragma unroll
        for (int j = 0; j < 4; ++j) {
          float av = ((const float*)&a[j])[u];
          acc0[j].x += av * w0.x; acc0[j].y += av * w0.y;
          acc0[j].z += av * w0.z; acc0[j].w += av * w0.w;
          acc1[j].x += av * w1.x; acc1[j].y += av * w1.y;
          acc1[j].z += av * w1.z; acc1[j].w += av * w1.w;
        }
      }
    }
  }

  float4 b0 = *(const float4*)&bias[c0];
  float4 b1 = *(const float4*)&bias[c1];
  #pragma unroll
  for (int j = 0; j < 4; ++j) {
    int r = base + ty * 4 + j;
    float4 o0, o1;
    o0.x = (acc0[j].x + b0.x) * scale; o0.y = (acc0[j].y + b0.y) * scale;
    o0.z = (acc0[j].z + b0.z) * scale; o0.w = (acc0[j].w + b0.w) * scale;
    o1.x = (acc1[j].x + b1.x) * scale; o1.y = (acc1[j].y + b1.y) * scale;
    o1.z = (acc1[j].z + b1.z) * scale; o1.w = (acc1[j].w + b1.w) * scale;
    *(float4*)&C[(size_t)r * 128 + c0] = o0;
    *(float4*)&C[(size_t)r * 128 + c1] = o1;
  }
}

// ---------------- SDDMM: score[e] = dot(q[dst[e]], k[src[e]]) ------------------
// 16 lanes per edge, 16 edges per 256-thread block.
__global__ __launch_bounds__(256) void sddmm(
    const float* __restrict__ q, const float* __restrict__ k,
    const int* __restrict__ src, const int* __restrict__ dst,
    float* __restrict__ score)
{
  int gt = blockIdx.x * 256 + threadIdx.x;
  int e = gt >> 4;
  int l = gt & 15;
  if (e >= N_EDGES) return;
  int s = src[e], d = dst[e];
  const float4* qp = (const float4*)(q + (size_t)d * 128) + l * 2;
  const float4* kp = (const float4*)(k + (size_t)s * 128) + l * 2;
  float4 q0 = qp[0], q1 = qp[1];
  float4 k0 = kp[0], k1 = kp[1];
  float acc = q0.x * k0.x + q0.y * k0.y + q0.z * k0.z + q0.w * k0.w
            + q1.x * k1.x + q1.y * k1.y + q1.z * k1.z + q1.w * k1.w;
  acc += __shfl_xor(acc, 1, 64);
  acc += __shfl_xor(acc, 2, 64);
  acc += __shfl_xor(acc, 4, 64);
  acc += __shfl_xor(acc, 8, 64);
  if (l == 0) score[e] = acc;
}

// ---------------- segmented max + exp-sum per destination node -----------------
__global__ __launch_bounds__(256) void seg_reduce(
    const float* __restrict__ score, const int* __restrict__ row_start,
    float* __restrict__ mbuf, float* __restrict__ sbuf)
{
  int i = blockIdx.x * 256 + threadIdx.x;
  if (i >= N_NODES) return;
  int r0 = row_start[i], r1 = row_start[i + 1];
  float m = -INFINITY;
  for (int e = r0; e < r1; ++e) m = fmaxf(m, score[e]);
  float s = 0.f;
  for (int e = r0; e < r1; ++e) s += __expf(score[e] - m);
  mbuf[i] = m;
  sbuf[i] = s;
}

// ---------------- SpMM: h[i] = sum_e attn_e * v[src_e], one wave per node ------
__global__ __launch_bounds__(256) void spmm(
    const float* __restrict__ score, const float* __restrict__ v,
    const int* __restrict__ src, const int* __restrict__ row_start,
    const float* __restrict__ mbuf, const float* __restrict__ sbuf,
    float* __restrict__ hout)
{
  int wid = (blockIdx.x * 256 + threadIdx.x) >> 6;
  int lane = threadIdx.x & 63;
  if (wid >= N_NODES) return;
  int r0 = row_start[wid], r1 = row_start[wid + 1];
  float m = mbuf[wid];
  float s = sbuf[wid];
  float inv = (s > 1e-20f) ? 1.0f / s : 0.0f;
  float2 acc = {0.f, 0.f};
  for (int e = r0; e < r1; ++e) {
    float a = __expf(score[e] - m) * inv;
    float2 vv = *(const float2*)(v + (size_t)src[e] * 128 + lane * 2);
    acc.x += a * vv.x;
    acc.y += a * vv.y;
  }
  *(float2*)(hout + (size_t)wid * 128 + lane * 2) = acc;
}

// ---------------- output head: logits = h @ Wout + bout, log_softmax -----------
// 4 waves per block, one node per wave; Wout staged in LDS.
__global__ __launch_bounds__(256) void out_head(
    const float* __restrict__ h, const float* __restrict__ Wout,
    const float* __restrict__ bout, float* __restrict__ out)
{
  __shared__ float Ws[HIDDEN * N_CLASSES];  // 20 KB
  int t = threadIdx.x;
  const float4* W4 = (const float4*)Wout;
  float4* S4 = (float4*)Ws;
  #pragma unroll
  for (int i = 0; i < 5; ++i) S4[t + 256 * i] = W4[t + 256 * i];
  __syncthreads();

  int wave = t >> 6, lane = t & 63;
  int node = blockIdx.x * 4 + wave;
  if (node >= N_NODES) return;
  const float* hp = h + (size_t)node * HIDDEN;
  int c = (lane < N_CLASSES) ? lane : 0;
  float logit = bout[c];
  #pragma unroll 4
  for (int kk = 0; kk < HIDDEN; ++kk) {
    logit += hp[kk] * Ws[kk * N_CLASSES + c];
  }
  float mv = (lane < N_CLASSES) ? logit : -INFINITY;
  #pragma unroll
  for (int off = 32; off >= 1; off >>= 1) mv = fmaxf(mv, __shfl_xor(mv, off, 64));
  float p = (lane < N_CLASSES) ? __expf(logit - mv) : 0.f;
  float sum = p;
  #pragma unroll
  for (int off = 32; off >= 1; off >>= 1) sum += __shfl_xor(sum, off, 64);
  float res = logit - mv - logf(sum);
  if (lane < N_CLASSES) out[(size_t)node * N_CLASSES + lane] = res;
}

extern "C" void kernel_launch(void* const* d_in, const int* in_sizes, int n_in,
                              void* d_out, int out_size, void* d_ws, size_t ws_size,
                              hipStream_t stream) {
  const float* h_in = (const float*)d_in[0];
  const int*   src  = (const int*)d_in[1];
  const int*   dst  = (const int*)d_in[2];
  const float* Wq   = (const float*)d_in[3];
  const float* bq   = (const float*)d_in[4];
  const float* Wk   = (const float*)d_in[5];
  const float* bk   = (const float*)d_in[6];
  const float* Wv   = (const float*)d_in[7];
  const float* bv   = (const float*)d_in[8];
  const float* Wout = (const float*)d_in[9];
  const float* bout = (const float*)d_in[10];
  float* out = (float*)d_out;

  char* ws = (char*)d_ws;
  size_t off = 0;
  auto alloc = [&](size_t bytes) -> void* {
    void* p = ws + off;
    off += (bytes + 255) & ~(size_t)255;
    return p;
  };
  int*   row_start = (int*)  alloc((size_t)(N_NODES + 1) * sizeof(int));
  float* q         = (float*)alloc((size_t)N_NODES * HIDDEN * sizeof(float));
  float* k         = (float*)alloc((size_t)N_NODES * HIDDEN * sizeof(float));
  float* v         = (float*)alloc((size_t)N_NODES * HIDDEN * sizeof(float));
  float* hbuf      = (float*)alloc((size_t)N_NODES * HIDDEN * sizeof(float));
  float* score     = (float*)alloc((size_t)N_EDGES * sizeof(float));
  float* mbuf      = (float*)alloc((size_t)N_NODES * sizeof(float));
  float* sbuf      = (float*)alloc((size_t)N_NODES * sizeof(float));

  build_csr<<<(N_NODES + 256) / 256, 256, 0, stream>>>(dst, row_start);

  const float* hcur = h_in;
  for (int l = 0; l < N_LAYERS; ++l) {
    const size_t wOff = (size_t)l * HIDDEN * HIDDEN;
    const size_t bOff = (size_t)l * HIDDEN;
    gemm_qkv<<<dim3(625, 3), 256, 0, stream>>>(
        hcur, Wq + wOff, Wk + wOff, Wv + wOff,
        bq + bOff, bk + bOff, bv + bOff, q, k, v);
    sddmm<<<(N_EDGES * 16) / 256, 256, 0, stream>>>(q, k, src, dst, score);
    seg_reduce<<<(N_NODES + 255) / 256, 256, 0, stream>>>(score, row_start, mbuf, sbuf);
    spmm<<<N_NODES / 4, 256, 0, stream>>>(score, v, src, row_start, mbuf, sbuf, hbuf);
    hcur = hbuf;
  }
  out_head<<<N_NODES / 4, 256, 0, stream>>>(hcur, Wout, bout, out);
}

// Round 2
// 498.256 us; speedup vs baseline: 1.5085x; 1.5085x over previous
//
#include <hip/hip_runtime.h>
#include <math.h>

#define N_NODES 40000
#define N_EDGES 640000
#define HIDDEN 128
#define N_LAYERS 4
#define N_CLASSES 40
#define SCALING 0.08838834764831845f

typedef __attribute__((ext_vector_type(8))) short short8;
typedef __attribute__((ext_vector_type(4))) float floatx4;

static __device__ __forceinline__ float b2f(unsigned short u) {
  return __uint_as_float(((unsigned)u) << 16);
}
static __device__ __forceinline__ unsigned short f2b(float f) {
  unsigned u = __float_as_uint(f);
  u += 0x7fff + ((u >> 16) & 1);   // round-to-nearest-even
  return (unsigned short)(u >> 16);
}

// ---------------- CSR build: row_start[i] = lower_bound(dst, i) ----------------
__global__ void build_csr(const int* __restrict__ dst, int* __restrict__ row_start) {
  int i = blockIdx.x * blockDim.x + threadIdx.x;
  if (i > N_NODES) return;
  int lo = 0, hi = N_EDGES;
  while (lo < hi) {
    int mid = (lo + hi) >> 1;
    if (dst[mid] < i) lo = mid + 1; else hi = mid;
  }
  row_start[i] = lo;
}

// ---------------- cast h (f32 -> bf16), 8 elems/thread -------------------------
__global__ __launch_bounds__(256) void cast_h(const float* __restrict__ in,
                                              unsigned short* __restrict__ out) {
  int i = blockIdx.x * 256 + threadIdx.x;
  if (i >= N_NODES * HIDDEN / 8) return;
  const float4* p = (const float4*)in + (size_t)i * 2;
  float4 a = p[0], b = p[1];
  union { unsigned short us[8]; uint4 v; } o;
  o.us[0] = f2b(a.x); o.us[1] = f2b(a.y); o.us[2] = f2b(a.z); o.us[3] = f2b(a.w);
  o.us[4] = f2b(b.x); o.us[5] = f2b(b.y); o.us[6] = f2b(b.z); o.us[7] = f2b(b.w);
  ((uint4*)out)[i] = o.v;
}

// ---------------- cast + transpose weights: wtb[l*3+m][n][k] = W[l][k][n] ------
__global__ __launch_bounds__(256) void cast_w(const float* __restrict__ Wq,
                                              const float* __restrict__ Wk,
                                              const float* __restrict__ Wv,
                                              unsigned short* __restrict__ wtb) {
  int idx = blockIdx.x * 256 + threadIdx.x;   // 12*16384 total
  if (idx >= 12 * 16384) return;
  int mat = idx >> 14;
  int rem = idx & 16383;
  int n = rem >> 7, kk = rem & 127;
  int l = mat / 3, m = mat % 3;
  const float* W = (m == 0) ? Wq : (m == 1) ? Wk : Wv;
  float val = W[(size_t)l * 16384 + (size_t)kk * 128 + n];
  wtb[(size_t)mat * 16384 + (size_t)n * 128 + kk] = f2b(val);
}

// ---------------- QKV GEMM via MFMA bf16 ---------------------------------------
// grid (313, 3), 256 thr = 4 waves x 32 rows = 128 rows/block, full 128 cols.
__global__ __launch_bounds__(256) void gemm_qkv_mfma(
    const unsigned short* __restrict__ A,     // 40000x128 bf16
    const unsigned short* __restrict__ wtb,   // 12 x [n][k] bf16
    const float* __restrict__ bq, const float* __restrict__ bk, const float* __restrict__ bv,
    unsigned short* __restrict__ q, unsigned short* __restrict__ k, unsigned short* __restrict__ v,
    int layer)
{
  int mat = blockIdx.y;
  const unsigned short* Wt = wtb + ((size_t)(layer * 3 + mat) << 14);
  const float* bias; unsigned short* C; float scale;
  if (mat == 0)      { bias = bq; C = q; scale = SCALING; }
  else if (mat == 1) { bias = bk; C = k; scale = 1.0f; }
  else               { bias = bv; C = v; scale = 1.0f; }

  const int wid = threadIdx.x >> 6, lane = threadIdx.x & 63;
  const int r = lane & 15, kg = lane >> 4;        // frag row/col + k-group
  const int row_base = blockIdx.x * 128 + wid * 32;

  int ar0 = row_base + r;      if (ar0 > N_NODES - 1) ar0 = N_NODES - 1;
  int ar1 = row_base + 16 + r; if (ar1 > N_NODES - 1) ar1 = N_NODES - 1;

  floatx4 acc[2][8];
  #pragma unroll
  for (int f = 0; f < 2; ++f)
    #pragma unroll
    for (int n = 0; n < 8; ++n) acc[f][n] = (floatx4){0.f, 0.f, 0.f, 0.f};

  const unsigned short* a0p = A + (size_t)ar0 * 128 + kg * 8;
  const unsigned short* a1p = A + (size_t)ar1 * 128 + kg * 8;
  const unsigned short* bp  = Wt + (size_t)r * 128 + kg * 8;

  #pragma unroll
  for (int kc = 0; kc < 128; kc += 32) {
    short8 a0 = *(const short8*)(a0p + kc);
    short8 a1 = *(const short8*)(a1p + kc);
    #pragma unroll
    for (int n = 0; n < 8; ++n) {
      short8 b = *(const short8*)(bp + n * 2048 + kc);
      acc[0][n] = __builtin_amdgcn_mfma_f32_16x16x32_bf16(a0, b, acc[0][n], 0, 0, 0);
      acc[1][n] = __builtin_amdgcn_mfma_f32_16x16x32_bf16(a1, b, acc[1][n], 0, 0, 0);
    }
  }

  // C/D layout: col = lane&15, row = (lane>>4)*4 + reg   [m89-verified]
  #pragma unroll
  for (int n = 0; n < 8; ++n) {
    float bn = bias[n * 16 + r];
    #pragma unroll
    for (int f = 0; f < 2; ++f) {
      int rb = row_base + f * 16 + kg * 4;
      #pragma unroll
      for (int g = 0; g < 4; ++g) {
        int row = rb + g;
        if (row < N_NODES)
          C[(size_t)row * 128 + n * 16 + r] = f2b((acc[f][n][g] + bn) * scale);
      }
    }
  }
}

// ---------------- SDDMM: score[e] = dot(q[dst[e]], k[src[e]]), bf16 loads ------
__global__ __launch_bounds__(256) void sddmm(
    const unsigned short* __restrict__ q, const unsigned short* __restrict__ k,
    const int* __restrict__ src, const int* __restrict__ dst,
    float* __restrict__ score)
{
  int gt = blockIdx.x * 256 + threadIdx.x;
  int e = gt >> 4;
  int l = gt & 15;
  if (e >= N_EDGES) return;
  int s = src[e], d = dst[e];
  short8 qv = *(const short8*)(q + (size_t)d * 128 + l * 8);
  short8 kv = *(const short8*)(k + (size_t)s * 128 + l * 8);
  float acc = 0.f;
  #pragma unroll
  for (int j = 0; j < 8; ++j)
    acc += b2f((unsigned short)qv[j]) * b2f((unsigned short)kv[j]);
  acc += __shfl_xor(acc, 1, 64);
  acc += __shfl_xor(acc, 2, 64);
  acc += __shfl_xor(acc, 4, 64);
  acc += __shfl_xor(acc, 8, 64);
  if (l == 0) score[e] = acc;
}

// ---------------- fused edge-softmax + SpMM, one wave per node -----------------
__global__ __launch_bounds__(256) void spmm_fused(
    const float* __restrict__ score, const unsigned short* __restrict__ v,
    const int* __restrict__ src, const int* __restrict__ row_start,
    unsigned short* __restrict__ hout)
{
  int lane = threadIdx.x & 63;
  int node = blockIdx.x * 4 + (threadIdx.x >> 6);
  if (node >= N_NODES) return;
  int r0 = row_start[node], r1 = row_start[node + 1];

  // lane-parallel max
  float ml = -INFINITY;
  for (int e = r0 + lane; e < r1; e += 64) ml = fmaxf(ml, score[e]);
  #pragma unroll
  for (int off = 32; off >= 1; off >>= 1) ml = fmaxf(ml, __shfl_xor(ml, off, 64));
  // lane-parallel exp-sum
  float sl = 0.f;
  for (int e = r0 + lane; e < r1; e += 64) sl += __expf(score[e] - ml);
  #pragma unroll
  for (int off = 32; off >= 1; off >>= 1) sl += __shfl_xor(sl, off, 64);
  float inv = (sl > 1e-20f) ? 1.0f / sl : 0.0f;

  float ax = 0.f, ay = 0.f;
  for (int c0 = r0; c0 < r1; c0 += 64) {
    int e = c0 + lane;
    bool valid = e < r1;
    float w = valid ? __expf(score[e] - ml) * inv : 0.f;
    int sj = valid ? src[e] : 0;
    int cnt = min(64, r1 - c0);
    int j = 0;
    for (; j + 4 <= cnt; j += 4) {
      float w0 = __shfl(w, j, 64),     w1 = __shfl(w, j + 1, 64);
      float w2 = __shfl(w, j + 2, 64), w3 = __shfl(w, j + 3, 64);
      int   i0 = __shfl(sj, j, 64),     i1 = __shfl(sj, j + 1, 64);
      int   i2 = __shfl(sj, j + 2, 64), i3 = __shfl(sj, j + 3, 64);
      unsigned u0 = *(const unsigned*)(v + (size_t)i0 * 128 + lane * 2);
      unsigned u1 = *(const unsigned*)(v + (size_t)i1 * 128 + lane * 2);
      unsigned u2 = *(const unsigned*)(v + (size_t)i2 * 128 + lane * 2);
      unsigned u3 = *(const unsigned*)(v + (size_t)i3 * 128 + lane * 2);
      ax += w0 * b2f((unsigned short)u0); ay += w0 * b2f((unsigned short)(u0 >> 16));
      ax += w1 * b2f((unsigned short)u1); ay += w1 * b2f((unsigned short)(u1 >> 16));
      ax += w2 * b2f((unsigned short)u2); ay += w2 * b2f((unsigned short)(u2 >> 16));
      ax += w3 * b2f((unsigned short)u3); ay += w3 * b2f((unsigned short)(u3 >> 16));
    }
    for (; j < cnt; ++j) {
      float w0 = __shfl(w, j, 64);
      int   i0 = __shfl(sj, j, 64);
      unsigned u0 = *(const unsigned*)(v + (size_t)i0 * 128 + lane * 2);
      ax += w0 * b2f((unsigned short)u0); ay += w0 * b2f((unsigned short)(u0 >> 16));
    }
  }
  unsigned outp = ((unsigned)f2b(ay) << 16) | (unsigned)f2b(ax);
  *(unsigned*)(hout + (size_t)node * 128 + lane * 2) = outp;
}

// ---------------- output head: logits = h @ Wout + bout, log_softmax -----------
__global__ __launch_bounds__(256) void out_head(
    const unsigned short* __restrict__ h, const float* __restrict__ Wout,
    const float* __restrict__ bout, float* __restrict__ out)
{
  __shared__ float Ws[HIDDEN * N_CLASSES];  // 20 KB
  int t = threadIdx.x;
  const float4* W4 = (const float4*)Wout;
  float4* S4 = (float4*)Ws;
  #pragma unroll
  for (int i = 0; i < 5; ++i) S4[t + 256 * i] = W4[t + 256 * i];
  __syncthreads();

  int wave = t >> 6, lane = t & 63;
  int node = blockIdx.x * 4 + wave;
  if (node >= N_NODES) return;
  const unsigned short* hp = h + (size_t)node * HIDDEN;
  int c = (lane < N_CLASSES) ? lane : 0;
  float logit = bout[c];
  #pragma unroll 4
  for (int kk = 0; kk < HIDDEN; ++kk) {
    logit += b2f(hp[kk]) * Ws[kk * N_CLASSES + c];
  }
  float mv = (lane < N_CLASSES) ? logit : -INFINITY;
  #pragma unroll
  for (int off = 32; off >= 1; off >>= 1) mv = fmaxf(mv, __shfl_xor(mv, off, 64));
  float p = (lane < N_CLASSES) ? __expf(logit - mv) : 0.f;
  float sum = p;
  #pragma unroll
  for (int off = 32; off >= 1; off >>= 1) sum += __shfl_xor(sum, off, 64);
  float res = logit - mv - logf(sum);
  if (lane < N_CLASSES) out[(size_t)node * N_CLASSES + lane] = res;
}

extern "C" void kernel_launch(void* const* d_in, const int* in_sizes, int n_in,
                              void* d_out, int out_size, void* d_ws, size_t ws_size,
                              hipStream_t stream) {
  const float* h_in = (const float*)d_in[0];
  const int*   src  = (const int*)d_in[1];
  const int*   dst  = (const int*)d_in[2];
  const float* Wq   = (const float*)d_in[3];
  const float* bq   = (const float*)d_in[4];
  const float* Wk   = (const float*)d_in[5];
  const float* bk   = (const float*)d_in[6];
  const float* Wv   = (const float*)d_in[7];
  const float* bv   = (const float*)d_in[8];
  const float* Wout = (const float*)d_in[9];
  const float* bout = (const float*)d_in[10];
  float* out = (float*)d_out;

  char* ws = (char*)d_ws;
  size_t off = 0;
  auto alloc = [&](size_t bytes) -> void* {
    void* p = ws + off;
    off += (bytes + 255) & ~(size_t)255;
    return p;
  };
  int*            row_start = (int*)           alloc((size_t)(N_NODES + 1) * sizeof(int));
  unsigned short* hb0       = (unsigned short*)alloc((size_t)N_NODES * HIDDEN * 2);
  unsigned short* hb1       = (unsigned short*)alloc((size_t)N_NODES * HIDDEN * 2);
  unsigned short* q         = (unsigned short*)alloc((size_t)N_NODES * HIDDEN * 2);
  unsigned short* k         = (unsigned short*)alloc((size_t)N_NODES * HIDDEN * 2);
  unsigned short* v         = (unsigned short*)alloc((size_t)N_NODES * HIDDEN * 2);
  float*          score     = (float*)         alloc((size_t)N_EDGES * sizeof(float));
  unsigned short* wtb       = (unsigned short*)alloc((size_t)12 * 16384 * 2);

  build_csr<<<(N_NODES + 256) / 256, 256, 0, stream>>>(dst, row_start);
  cast_h<<<(N_NODES * HIDDEN / 8 + 255) / 256, 256, 0, stream>>>(h_in, hb0);
  cast_w<<<(12 * 16384 + 255) / 256, 256, 0, stream>>>(Wq, Wk, Wv, wtb);

  unsigned short* hcur = hb0;
  unsigned short* hnext = hb1;
  for (int l = 0; l < N_LAYERS; ++l) {
    gemm_qkv_mfma<<<dim3(313, 3), 256, 0, stream>>>(
        hcur, wtb, bq + (size_t)l * HIDDEN, bk + (size_t)l * HIDDEN, bv + (size_t)l * HIDDEN,
        q, k, v, l);
    sddmm<<<(N_EDGES * 16) / 256, 256, 0, stream>>>(q, k, src, dst, score);
    spmm_fused<<<N_NODES / 4, 256, 0, stream>>>(score, v, src, row_start, hnext);
    unsigned short* tmp = hcur; hcur = hnext; hnext = tmp;
  }
  out_head<<<N_NODES / 4, 256, 0, stream>>>(hcur, Wout, bout, out);
}

// Round 3
// 415.539 us; speedup vs baseline: 1.8088x; 1.1991x over previous
//
#include <hip/hip_runtime.h>
#include <math.h>

#define N_NODES 40000
#define N_EDGES 640000
#define HIDDEN 128
#define N_LAYERS 4
#define N_CLASSES 40
#define SCALING 0.08838834764831845f

typedef __attribute__((ext_vector_type(8))) short short8;
typedef __attribute__((ext_vector_type(4))) float floatx4;

static __device__ __forceinline__ float b2f(unsigned short u) {
  return __uint_as_float(((unsigned)u) << 16);
}
static __device__ __forceinline__ unsigned short f2b(float f) {
  unsigned u = __float_as_uint(f);
  u += 0x7fff + ((u >> 16) & 1);   // round-to-nearest-even
  return (unsigned short)(u >> 16);
}

// ---------------- CSR build: row_start[i] = lower_bound(dst, i) ----------------
__global__ void build_csr(const int* __restrict__ dst, int* __restrict__ row_start) {
  int i = blockIdx.x * blockDim.x + threadIdx.x;
  if (i > N_NODES) return;
  int lo = 0, hi = N_EDGES;
  while (lo < hi) {
    int mid = (lo + hi) >> 1;
    if (dst[mid] < i) lo = mid + 1; else hi = mid;
  }
  row_start[i] = lo;
}

// ---------------- cast h (f32 -> bf16), 8 elems/thread -------------------------
__global__ __launch_bounds__(256) void cast_h(const float* __restrict__ in,
                                              unsigned short* __restrict__ out) {
  int i = blockIdx.x * 256 + threadIdx.x;
  if (i >= N_NODES * HIDDEN / 8) return;
  const float4* p = (const float4*)in + (size_t)i * 2;
  float4 a = p[0], b = p[1];
  union { unsigned short us[8]; uint4 v; } o;
  o.us[0] = f2b(a.x); o.us[1] = f2b(a.y); o.us[2] = f2b(a.z); o.us[3] = f2b(a.w);
  o.us[4] = f2b(b.x); o.us[5] = f2b(b.y); o.us[6] = f2b(b.z); o.us[7] = f2b(b.w);
  ((uint4*)out)[i] = o.v;
}

// ---------------- cast + transpose weights: wtb[l*3+m][n][k] = W[l][k][n] ------
__global__ __launch_bounds__(256) void cast_w(const float* __restrict__ Wq,
                                              const float* __restrict__ Wk,
                                              const float* __restrict__ Wv,
                                              unsigned short* __restrict__ wtb) {
  int idx = blockIdx.x * 256 + threadIdx.x;   // 12*16384 total
  if (idx >= 12 * 16384) return;
  int mat = idx >> 14;
  int rem = idx & 16383;
  int n = rem >> 7, kk = rem & 127;
  int l = mat / 3, m = mat % 3;
  const float* W = (m == 0) ? Wq : (m == 1) ? Wk : Wv;
  float val = W[(size_t)l * 16384 + (size_t)kk * 128 + n];
  wtb[(size_t)mat * 16384 + (size_t)n * 128 + kk] = f2b(val);
}

// ---------------- cast + transpose + pad Wout: wout_t[48][128] -----------------
__global__ __launch_bounds__(256) void cast_wout(const float* __restrict__ Wout,
                                                 unsigned short* __restrict__ wout_t) {
  int idx = blockIdx.x * 256 + threadIdx.x;   // 48*128 = 6144
  if (idx >= 48 * 128) return;
  int n = idx >> 7, kk = idx & 127;
  float val = (n < N_CLASSES) ? Wout[(size_t)kk * N_CLASSES + n] : 0.f;
  wout_t[idx] = f2b(val);
}

// ---------------- QKV GEMM via MFMA bf16 ---------------------------------------
// grid (313, 3), 256 thr = 4 waves x 32 rows = 128 rows/block, full 128 cols.
__global__ __launch_bounds__(256) void gemm_qkv_mfma(
    const unsigned short* __restrict__ A,     // 40000x128 bf16
    const unsigned short* __restrict__ wtb,   // 12 x [n][k] bf16
    const float* __restrict__ bq, const float* __restrict__ bk, const float* __restrict__ bv,
    unsigned short* __restrict__ q, unsigned short* __restrict__ k, unsigned short* __restrict__ v,
    int layer)
{
  int mat = blockIdx.y;
  const unsigned short* Wt = wtb + ((size_t)(layer * 3 + mat) << 14);
  const float* bias; unsigned short* C; float scale;
  if (mat == 0)      { bias = bq; C = q; scale = SCALING; }
  else if (mat == 1) { bias = bk; C = k; scale = 1.0f; }
  else               { bias = bv; C = v; scale = 1.0f; }

  const int wid = threadIdx.x >> 6, lane = threadIdx.x & 63;
  const int r = lane & 15, kg = lane >> 4;        // frag row/col + k-group
  const int row_base = blockIdx.x * 128 + wid * 32;

  int ar0 = row_base + r;      if (ar0 > N_NODES - 1) ar0 = N_NODES - 1;
  int ar1 = row_base + 16 + r; if (ar1 > N_NODES - 1) ar1 = N_NODES - 1;

  floatx4 acc[2][8];
  #pragma unroll
  for (int f = 0; f < 2; ++f)
    #pragma unroll
    for (int n = 0; n < 8; ++n) acc[f][n] = (floatx4){0.f, 0.f, 0.f, 0.f};

  const unsigned short* a0p = A + (size_t)ar0 * 128 + kg * 8;
  const unsigned short* a1p = A + (size_t)ar1 * 128 + kg * 8;
  const unsigned short* bp  = Wt + (size_t)r * 128 + kg * 8;

  #pragma unroll
  for (int kc = 0; kc < 128; kc += 32) {
    short8 a0 = *(const short8*)(a0p + kc);
    short8 a1 = *(const short8*)(a1p + kc);
    #pragma unroll
    for (int n = 0; n < 8; ++n) {
      short8 b = *(const short8*)(bp + n * 2048 + kc);
      acc[0][n] = __builtin_amdgcn_mfma_f32_16x16x32_bf16(a0, b, acc[0][n], 0, 0, 0);
      acc[1][n] = __builtin_amdgcn_mfma_f32_16x16x32_bf16(a1, b, acc[1][n], 0, 0, 0);
    }
  }

  // C/D layout: col = lane&15, row = (lane>>4)*4 + reg
  #pragma unroll
  for (int n = 0; n < 8; ++n) {
    float bn = bias[n * 16 + r];
    #pragma unroll
    for (int f = 0; f < 2; ++f) {
      int rb = row_base + f * 16 + kg * 4;
      #pragma unroll
      for (int g = 0; g < 4; ++g) {
        int row = rb + g;
        if (row < N_NODES)
          C[(size_t)row * 128 + n * 16 + r] = f2b((acc[f][n][g] + bn) * scale);
      }
    }
  }
}

// ---------------- fused edge attention: SDDMM + softmax + SpMM -----------------
// One wave per destination node. 16-lane subgroups each handle one edge's dot;
// all 64 lanes accumulate v. No max-subtraction (scores bounded, exp safe).
__global__ __launch_bounds__(256) void edge_fused(
    const unsigned short* __restrict__ q, const unsigned short* __restrict__ k,
    const unsigned short* __restrict__ v,
    const int* __restrict__ src, const int* __restrict__ row_start,
    unsigned short* __restrict__ hout)
{
  const int lane = threadIdx.x & 63;
  const int node = blockIdx.x * 4 + (threadIdx.x >> 6);   // 40000 % 4 == 0
  const int sg = lane >> 4, sl = lane & 15;

  // q fragment: subgroup lane sl owns q[node][sl*8 .. sl*8+8)
  short8 qf = *(const short8*)(q + (size_t)node * 128 + sl * 8);
  float qd[8];
  #pragma unroll
  for (int j = 0; j < 8; ++j) qd[j] = b2f((unsigned short)qf[j]);

  int r0 = row_start[node], r1 = row_start[node + 1];

  float sum = 0.f, ax = 0.f, ay = 0.f;

  for (int c0 = r0; c0 < r1; c0 += 4) {
    int cnt = min(4, r1 - c0);
    // ---- phase 1: subgroup sg computes exp(score) of edge c0+sg ----
    float w = 0.f;
    int sidx = 0;
    if (sg < cnt) {
      sidx = src[c0 + sg];
      short8 kf = *(const short8*)(k + (size_t)sidx * 128 + sl * 8);
      float d = 0.f;
      #pragma unroll
      for (int j = 0; j < 8; ++j) d += qd[j] * b2f((unsigned short)kf[j]);
      d += __shfl_xor(d, 1, 64);
      d += __shfl_xor(d, 2, 64);
      d += __shfl_xor(d, 4, 64);
      d += __shfl_xor(d, 8, 64);
      w = __expf(d);
    }
    // ---- phase 2: all lanes accumulate the (up to) 4 v rows ----
    if (cnt == 4) {
      float w0 = __shfl(w, 0, 64),  w1 = __shfl(w, 16, 64);
      float w2 = __shfl(w, 32, 64), w3 = __shfl(w, 48, 64);
      int   i0 = __shfl(sidx, 0, 64),  i1 = __shfl(sidx, 16, 64);
      int   i2 = __shfl(sidx, 32, 64), i3 = __shfl(sidx, 48, 64);
      unsigned u0 = *(const unsigned*)(v + (size_t)i0 * 128 + lane * 2);
      unsigned u1 = *(const unsigned*)(v + (size_t)i1 * 128 + lane * 2);
      unsigned u2 = *(const unsigned*)(v + (size_t)i2 * 128 + lane * 2);
      unsigned u3 = *(const unsigned*)(v + (size_t)i3 * 128 + lane * 2);
      sum += (w0 + w1) + (w2 + w3);
      ax += w0 * b2f((unsigned short)u0); ay += w0 * b2f((unsigned short)(u0 >> 16));
      ax += w1 * b2f((unsigned short)u1); ay += w1 * b2f((unsigned short)(u1 >> 16));
      ax += w2 * b2f((unsigned short)u2); ay += w2 * b2f((unsigned short)(u2 >> 16));
      ax += w3 * b2f((unsigned short)u3); ay += w3 * b2f((unsigned short)(u3 >> 16));
    } else {
      for (int i = 0; i < cnt; ++i) {
        float wi = __shfl(w, i * 16, 64);
        int   ii = __shfl(sidx, i * 16, 64);
        unsigned u = *(const unsigned*)(v + (size_t)ii * 128 + lane * 2);
        sum += wi;
        ax += wi * b2f((unsigned short)u); ay += wi * b2f((unsigned short)(u >> 16));
      }
    }
  }

  float inv = (sum > 1e-20f) ? 1.0f / sum : 0.0f;
  unsigned outp = ((unsigned)f2b(ay * inv) << 16) | (unsigned)f2b(ax * inv);
  *(unsigned*)(hout + (size_t)node * 128 + lane * 2) = outp;
}

// ---------------- output head via MFMA: logits + log_softmax -------------------
// grid 313 x 256 thr; wave = 32 nodes x 48 classes (40 valid).
__global__ __launch_bounds__(256) void out_head_mfma(
    const unsigned short* __restrict__ h, const unsigned short* __restrict__ wout_t,
    const float* __restrict__ bout, float* __restrict__ out)
{
  const int wid = threadIdx.x >> 6, lane = threadIdx.x & 63;
  const int r = lane & 15, kg = lane >> 4;
  const int row_base = blockIdx.x * 128 + wid * 32;

  int ar0 = row_base + r;      if (ar0 > N_NODES - 1) ar0 = N_NODES - 1;
  int ar1 = row_base + 16 + r; if (ar1 > N_NODES - 1) ar1 = N_NODES - 1;

  floatx4 acc[2][3];
  #pragma unroll
  for (int f = 0; f < 2; ++f)
    #pragma unroll
    for (int n = 0; n < 3; ++n) acc[f][n] = (floatx4){0.f, 0.f, 0.f, 0.f};

  const unsigned short* a0p = h + (size_t)ar0 * 128 + kg * 8;
  const unsigned short* a1p = h + (size_t)ar1 * 128 + kg * 8;
  const unsigned short* bp  = wout_t + (size_t)r * 128 + kg * 8;

  #pragma unroll
  for (int kc = 0; kc < 128; kc += 32) {
    short8 a0 = *(const short8*)(a0p + kc);
    short8 a1 = *(const short8*)(a1p + kc);
    #pragma unroll
    for (int n = 0; n < 3; ++n) {
      short8 b = *(const short8*)(bp + n * 2048 + kc);
      acc[0][n] = __builtin_amdgcn_mfma_f32_16x16x32_bf16(a0, b, acc[0][n], 0, 0, 0);
      acc[1][n] = __builtin_amdgcn_mfma_f32_16x16x32_bf16(a1, b, acc[1][n], 0, 0, 0);
    }
  }

  // bias per class fragment (class = n*16 + r)
  float bn0 = bout[r];
  float bn1 = bout[16 + r];
  float bn2 = (r < 8) ? bout[32 + r] : 0.f;

  #pragma unroll
  for (int f = 0; f < 2; ++f) {
    #pragma unroll
    for (int g = 0; g < 4; ++g) {
      int row = row_base + f * 16 + kg * 4 + g;
      float l0 = acc[f][0][g] + bn0;
      float l1 = acc[f][1][g] + bn1;
      float l2 = acc[f][2][g] + bn2;          // valid only if r < 8
      // max over 40 classes (lanes sharing kg hold cols 0..15 of the 3 frags)
      float m = fmaxf(l0, l1);
      if (r < 8) m = fmaxf(m, l2);
      #pragma unroll
      for (int off = 8; off >= 1; off >>= 1) m = fmaxf(m, __shfl_xor(m, off, 64));
      float s = __expf(l0 - m) + __expf(l1 - m) + ((r < 8) ? __expf(l2 - m) : 0.f);
      #pragma unroll
      for (int off = 8; off >= 1; off >>= 1) s += __shfl_xor(s, off, 64);
      float lse = m + logf(s);
      if (row < N_NODES) {
        float* op = out + (size_t)row * N_CLASSES;
        op[r]      = l0 - lse;
        op[16 + r] = l1 - lse;
        if (r < 8) op[32 + r] = l2 - lse;
      }
    }
  }
}

extern "C" void kernel_launch(void* const* d_in, const int* in_sizes, int n_in,
                              void* d_out, int out_size, void* d_ws, size_t ws_size,
                              hipStream_t stream) {
  const float* h_in = (const float*)d_in[0];
  const int*   src  = (const int*)d_in[1];
  const int*   dst  = (const int*)d_in[2];
  const float* Wq   = (const float*)d_in[3];
  const float* bq   = (const float*)d_in[4];
  const float* Wk   = (const float*)d_in[5];
  const float* bk   = (const float*)d_in[6];
  const float* Wv   = (const float*)d_in[7];
  const float* bv   = (const float*)d_in[8];
  const float* Wout = (const float*)d_in[9];
  const float* bout = (const float*)d_in[10];
  float* out = (float*)d_out;

  char* ws = (char*)d_ws;
  size_t off = 0;
  auto alloc = [&](size_t bytes) -> void* {
    void* p = ws + off;
    off += (bytes + 255) & ~(size_t)255;
    return p;
  };
  int*            row_start = (int*)           alloc((size_t)(N_NODES + 1) * sizeof(int));
  unsigned short* hb0       = (unsigned short*)alloc((size_t)N_NODES * HIDDEN * 2);
  unsigned short* hb1       = (unsigned short*)alloc((size_t)N_NODES * HIDDEN * 2);
  unsigned short* q         = (unsigned short*)alloc((size_t)N_NODES * HIDDEN * 2);
  unsigned short* k         = (unsigned short*)alloc((size_t)N_NODES * HIDDEN * 2);
  unsigned short* v         = (unsigned short*)alloc((size_t)N_NODES * HIDDEN * 2);
  unsigned short* wtb       = (unsigned short*)alloc((size_t)12 * 16384 * 2);
  unsigned short* wout_t    = (unsigned short*)alloc((size_t)48 * 128 * 2);

  build_csr<<<(N_NODES + 256) / 256, 256, 0, stream>>>(dst, row_start);
  cast_h<<<(N_NODES * HIDDEN / 8 + 255) / 256, 256, 0, stream>>>(h_in, hb0);
  cast_w<<<(12 * 16384 + 255) / 256, 256, 0, stream>>>(Wq, Wk, Wv, wtb);
  cast_wout<<<(48 * 128 + 255) / 256, 256, 0, stream>>>(Wout, wout_t);

  unsigned short* hcur = hb0;
  unsigned short* hnext = hb1;
  for (int l = 0; l < N_LAYERS; ++l) {
    gemm_qkv_mfma<<<dim3(313, 3), 256, 0, stream>>>(
        hcur, wtb, bq + (size_t)l * HIDDEN, bk + (size_t)l * HIDDEN, bv + (size_t)l * HIDDEN,
        q, k, v, l);
    edge_fused<<<N_NODES / 4, 256, 0, stream>>>(q, k, v, src, row_start, hnext);
    unsigned short* tmp = hcur; hcur = hnext; hnext = tmp;
  }
  out_head_mfma<<<313, 256, 0, stream>>>(hcur, wout_t, bout, out);
}

// Round 4
// 322.637 us; speedup vs baseline: 2.3296x; 1.2879x over previous
//
#include <hip/hip_runtime.h>
#include <math.h>

#define N_NODES 40000
#define N_EDGES 640000
#define HIDDEN 128
#define N_LAYERS 4
#define N_CLASSES 40
#define SCALING 0.08838834764831845f

typedef __attribute__((ext_vector_type(8))) short short8;
typedef __attribute__((ext_vector_type(4))) float floatx4;

static __device__ __forceinline__ float b2f(unsigned short u) {
  return __uint_as_float(((unsigned)u) << 16);
}
static __device__ __forceinline__ unsigned short f2b(float f) {
  unsigned u = __float_as_uint(f);
  u += 0x7fff + ((u >> 16) & 1);   // round-to-nearest-even
  return (unsigned short)(u >> 16);
}

// ---------------- CSR build: row_start[i] = lower_bound(dst, i) ----------------
__global__ void build_csr(const int* __restrict__ dst, int* __restrict__ row_start) {
  int i = blockIdx.x * blockDim.x + threadIdx.x;
  if (i > N_NODES) return;
  int lo = 0, hi = N_EDGES;
  while (lo < hi) {
    int mid = (lo + hi) >> 1;
    if (dst[mid] < i) lo = mid + 1; else hi = mid;
  }
  row_start[i] = lo;
}

// ---------------- cast h (f32 -> bf16), 8 elems/thread -------------------------
__global__ __launch_bounds__(256) void cast_h(const float* __restrict__ in,
                                              unsigned short* __restrict__ out) {
  int i = blockIdx.x * 256 + threadIdx.x;
  if (i >= N_NODES * HIDDEN / 8) return;
  const float4* p = (const float4*)in + (size_t)i * 2;
  float4 a = p[0], b = p[1];
  union { unsigned short us[8]; uint4 v; } o;
  o.us[0] = f2b(a.x); o.us[1] = f2b(a.y); o.us[2] = f2b(a.z); o.us[3] = f2b(a.w);
  o.us[4] = f2b(b.x); o.us[5] = f2b(b.y); o.us[6] = f2b(b.z); o.us[7] = f2b(b.w);
  ((uint4*)out)[i] = o.v;
}

// ---------------- cast + transpose weights: wtb[l*3+m][n][k] = W[l][k][n] ------
__global__ __launch_bounds__(256) void cast_w(const float* __restrict__ Wq,
                                              const float* __restrict__ Wk,
                                              const float* __restrict__ Wv,
                                              unsigned short* __restrict__ wtb) {
  int idx = blockIdx.x * 256 + threadIdx.x;   // 12*16384 total
  if (idx >= 12 * 16384) return;
  int mat = idx >> 14;
  int rem = idx & 16383;
  int n = rem >> 7, kk = rem & 127;
  int l = mat / 3, m = mat % 3;
  const float* W = (m == 0) ? Wq : (m == 1) ? Wk : Wv;
  float val = W[(size_t)l * 16384 + (size_t)kk * 128 + n];
  wtb[(size_t)mat * 16384 + (size_t)n * 128 + kk] = f2b(val);
}

// ---------------- cast + transpose + pad Wout: wout_t[48][128] -----------------
__global__ __launch_bounds__(256) void cast_wout(const float* __restrict__ Wout,
                                                 unsigned short* __restrict__ wout_t) {
  int idx = blockIdx.x * 256 + threadIdx.x;   // 48*128 = 6144
  if (idx >= 48 * 128) return;
  int n = idx >> 7, kk = idx & 127;
  float val = (n < N_CLASSES) ? Wout[(size_t)kk * N_CLASSES + n] : 0.f;
  wout_t[idx] = f2b(val);
}

// ---------------- QKV GEMM via MFMA bf16, swapped operands ---------------------
// D[dim][node]: A-operand = Wt rows (dims), B-operand = h rows (nodes).
// Each lane ends with 4 CONSECUTIVE dims per (df,f) -> packed 8B stores.
// grid (313, 3), 256 thr = 4 waves x 32 rows.
__global__ __launch_bounds__(256) void gemm_qkv_mfma(
    const unsigned short* __restrict__ A,     // 40000x128 bf16
    const unsigned short* __restrict__ wtb,   // 12 x [n][k] bf16
    const float* __restrict__ bq, const float* __restrict__ bk, const float* __restrict__ bv,
    unsigned short* __restrict__ q, unsigned short* __restrict__ k, unsigned short* __restrict__ v,
    int layer)
{
  int mat = blockIdx.y;
  const unsigned short* Wt = wtb + ((size_t)(layer * 3 + mat) << 14);
  const float* bias; unsigned short* C; float scale;
  if (mat == 0)      { bias = bq; C = q; scale = SCALING; }
  else if (mat == 1) { bias = bk; C = k; scale = 1.0f; }
  else               { bias = bv; C = v; scale = 1.0f; }

  const int wid = threadIdx.x >> 6, lane = threadIdx.x & 63;
  const int r = lane & 15, kg = lane >> 4;
  const int row_base = blockIdx.x * 128 + wid * 32;

  int ar0 = row_base + r;      if (ar0 > N_NODES - 1) ar0 = N_NODES - 1;
  int ar1 = row_base + 16 + r; if (ar1 > N_NODES - 1) ar1 = N_NODES - 1;

  // h fragments (B-operand): loaded once, reused across all 8 dim-frags
  short8 hf[2][4];
  #pragma unroll
  for (int kc = 0; kc < 4; ++kc) {
    hf[0][kc] = *(const short8*)(A + (size_t)ar0 * 128 + kc * 32 + kg * 8);
    hf[1][kc] = *(const short8*)(A + (size_t)ar1 * 128 + kc * 32 + kg * 8);
  }

  floatx4 acc[8][2];
  #pragma unroll
  for (int df = 0; df < 8; ++df) {
    acc[df][0] = (floatx4){0.f, 0.f, 0.f, 0.f};
    acc[df][1] = (floatx4){0.f, 0.f, 0.f, 0.f};
  }

  const unsigned short* wp = Wt + (size_t)r * 128 + kg * 8;
  #pragma unroll
  for (int df = 0; df < 8; ++df) {
    #pragma unroll
    for (int kc = 0; kc < 4; ++kc) {
      short8 wf = *(const short8*)(wp + df * 2048 + kc * 32);
      acc[df][0] = __builtin_amdgcn_mfma_f32_16x16x32_bf16(wf, hf[0][kc], acc[df][0], 0, 0, 0);
      acc[df][1] = __builtin_amdgcn_mfma_f32_16x16x32_bf16(wf, hf[1][kc], acc[df][1], 0, 0, 0);
    }
  }

  // D layout: col(lane&15) = node, row((lane>>4)*4+g) = dim_local
  #pragma unroll
  for (int df = 0; df < 8; ++df) {
    float4 b4 = *(const float4*)&bias[df * 16 + kg * 4];
    #pragma unroll
    for (int f = 0; f < 2; ++f) {
      int node = row_base + f * 16 + r;
      if (node < N_NODES) {
        union { unsigned short us[4]; uint2 u2; } o;
        o.us[0] = f2b((acc[df][f][0] + b4.x) * scale);
        o.us[1] = f2b((acc[df][f][1] + b4.y) * scale);
        o.us[2] = f2b((acc[df][f][2] + b4.z) * scale);
        o.us[3] = f2b((acc[df][f][3] + b4.w) * scale);
        *(uint2*)(C + (size_t)node * 128 + df * 16 + kg * 4) = o.u2;
      }
    }
  }
}

// ---------------- fused edge attention: SDDMM + softmax + SpMM -----------------
// One wave per dst node; each 16-lane subgroup owns one edge end-to-end
// (dot AND v-accumulate into per-lane dim partials). 2-stage pipeline.
__global__ __launch_bounds__(256) void edge_fused(
    const unsigned short* __restrict__ q, const unsigned short* __restrict__ k,
    const unsigned short* __restrict__ v,
    const int* __restrict__ src, const int* __restrict__ row_start,
    unsigned short* __restrict__ hout)
{
  const int lane = threadIdx.x & 63;
  const int node = blockIdx.x * 4 + (threadIdx.x >> 6);   // 40000 % 4 == 0
  const int sg = lane >> 4, sl = lane & 15;

  short8 qf = *(const short8*)(q + (size_t)node * 128 + sl * 8);
  float qd[8];
  #pragma unroll
  for (int j = 0; j < 8; ++j) qd[j] = b2f((unsigned short)qf[j]);

  const int r0 = row_start[node], r1 = row_start[node + 1];

  float acc[8] = {0.f, 0.f, 0.f, 0.f, 0.f, 0.f, 0.f, 0.f};
  float ws = 0.f;

  // prologue: load first edge group
  bool valid = (r0 + sg) < r1;
  int sidx = valid ? src[r0 + sg] : 0;
  short8 kf = *(const short8*)(k + (size_t)sidx * 128 + sl * 8);
  short8 vf = *(const short8*)(v + (size_t)sidx * 128 + sl * 8);

  for (int c0 = r0; c0 < r1; c0 += 4) {
    // prefetch next group (loads issue before current compute's chain)
    int cn = c0 + 4;
    bool nvalid = (cn + sg) < r1;
    int nsidx = nvalid ? src[cn + sg] : 0;
    short8 nkf = *(const short8*)(k + (size_t)nsidx * 128 + sl * 8);
    short8 nvf = *(const short8*)(v + (size_t)nsidx * 128 + sl * 8);

    // current: dot over this subgroup's 16 lanes
    float d = 0.f;
    #pragma unroll
    for (int j = 0; j < 8; ++j) d += qd[j] * b2f((unsigned short)kf[j]);
    d += __shfl_xor(d, 1, 64);
    d += __shfl_xor(d, 2, 64);
    d += __shfl_xor(d, 4, 64);
    d += __shfl_xor(d, 8, 64);
    float w = valid ? __expf(d) : 0.f;
    ws += w;
    #pragma unroll
    for (int j = 0; j < 8; ++j) acc[j] += w * b2f((unsigned short)vf[j]);

    valid = nvalid; kf = nkf; vf = nvf;
  }

  // combine the 4 subgroups (same dim mapping across sg)
  #pragma unroll
  for (int off = 16; off <= 32; off <<= 1) {
    ws += __shfl_xor(ws, off, 64);
    #pragma unroll
    for (int j = 0; j < 8; ++j) acc[j] += __shfl_xor(acc[j], off, 64);
  }

  if (sg == 0) {
    float inv = (ws > 1e-20f) ? 1.0f / ws : 0.0f;
    union { unsigned short us[8]; uint4 u4; } o;
    #pragma unroll
    for (int j = 0; j < 8; ++j) o.us[j] = f2b(acc[j] * inv);
    *(uint4*)(hout + (size_t)node * 128 + sl * 8) = o.u4;
  }
}

// ---------------- output head via MFMA: logits + log_softmax -------------------
// grid 313 x 256 thr; wave = 32 nodes x 48 classes (40 valid).
__global__ __launch_bounds__(256) void out_head_mfma(
    const unsigned short* __restrict__ h, const unsigned short* __restrict__ wout_t,
    const float* __restrict__ bout, float* __restrict__ out)
{
  const int wid = threadIdx.x >> 6, lane = threadIdx.x & 63;
  const int r = lane & 15, kg = lane >> 4;
  const int row_base = blockIdx.x * 128 + wid * 32;

  int ar0 = row_base + r;      if (ar0 > N_NODES - 1) ar0 = N_NODES - 1;
  int ar1 = row_base + 16 + r; if (ar1 > N_NODES - 1) ar1 = N_NODES - 1;

  floatx4 acc[2][3];
  #pragma unroll
  for (int f = 0; f < 2; ++f)
    #pragma unroll
    for (int n = 0; n < 3; ++n) acc[f][n] = (floatx4){0.f, 0.f, 0.f, 0.f};

  const unsigned short* a0p = h + (size_t)ar0 * 128 + kg * 8;
  const unsigned short* a1p = h + (size_t)ar1 * 128 + kg * 8;
  const unsigned short* bp  = wout_t + (size_t)r * 128 + kg * 8;

  #pragma unroll
  for (int kc = 0; kc < 128; kc += 32) {
    short8 a0 = *(const short8*)(a0p + kc);
    short8 a1 = *(const short8*)(a1p + kc);
    #pragma unroll
    for (int n = 0; n < 3; ++n) {
      short8 b = *(const short8*)(bp + n * 2048 + kc);
      acc[0][n] = __builtin_amdgcn_mfma_f32_16x16x32_bf16(a0, b, acc[0][n], 0, 0, 0);
      acc[1][n] = __builtin_amdgcn_mfma_f32_16x16x32_bf16(a1, b, acc[1][n], 0, 0, 0);
    }
  }

  float bn0 = bout[r];
  float bn1 = bout[16 + r];
  float bn2 = (r < 8) ? bout[32 + r] : 0.f;

  #pragma unroll
  for (int f = 0; f < 2; ++f) {
    #pragma unroll
    for (int g = 0; g < 4; ++g) {
      int row = row_base + f * 16 + kg * 4 + g;
      float l0 = acc[f][0][g] + bn0;
      float l1 = acc[f][1][g] + bn1;
      float l2 = acc[f][2][g] + bn2;          // valid only if r < 8
      float m = fmaxf(l0, l1);
      if (r < 8) m = fmaxf(m, l2);
      #pragma unroll
      for (int off = 8; off >= 1; off >>= 1) m = fmaxf(m, __shfl_xor(m, off, 64));
      float s = __expf(l0 - m) + __expf(l1 - m) + ((r < 8) ? __expf(l2 - m) : 0.f);
      #pragma unroll
      for (int off = 8; off >= 1; off >>= 1) s += __shfl_xor(s, off, 64);
      float lse = m + logf(s);
      if (row < N_NODES) {
        float* op = out + (size_t)row * N_CLASSES;
        op[r]      = l0 - lse;
        op[16 + r] = l1 - lse;
        if (r < 8) op[32 + r] = l2 - lse;
      }
    }
  }
}

extern "C" void kernel_launch(void* const* d_in, const int* in_sizes, int n_in,
                              void* d_out, int out_size, void* d_ws, size_t ws_size,
                              hipStream_t stream) {
  const float* h_in = (const float*)d_in[0];
  const int*   src  = (const int*)d_in[1];
  const int*   dst  = (const int*)d_in[2];
  const float* Wq   = (const float*)d_in[3];
  const float* bq   = (const float*)d_in[4];
  const float* Wk   = (const float*)d_in[5];
  const float* bk   = (const float*)d_in[6];
  const float* Wv   = (const float*)d_in[7];
  const float* bv   = (const float*)d_in[8];
  const float* Wout = (const float*)d_in[9];
  const float* bout = (const float*)d_in[10];
  float* out = (float*)d_out;

  char* ws = (char*)d_ws;
  size_t off = 0;
  auto alloc = [&](size_t bytes) -> void* {
    void* p = ws + off;
    off += (bytes + 255) & ~(size_t)255;
    return p;
  };
  int*            row_start = (int*)           alloc((size_t)(N_NODES + 1) * sizeof(int));
  unsigned short* hb0       = (unsigned short*)alloc((size_t)N_NODES * HIDDEN * 2);
  unsigned short* hb1       = (unsigned short*)alloc((size_t)N_NODES * HIDDEN * 2);
  unsigned short* q         = (unsigned short*)alloc((size_t)N_NODES * HIDDEN * 2);
  unsigned short* k         = (unsigned short*)alloc((size_t)N_NODES * HIDDEN * 2);
  unsigned short* v         = (unsigned short*)alloc((size_t)N_NODES * HIDDEN * 2);
  unsigned short* wtb       = (unsigned short*)alloc((size_t)12 * 16384 * 2);
  unsigned short* wout_t    = (unsigned short*)alloc((size_t)48 * 128 * 2);

  build_csr<<<(N_NODES + 256) / 256, 256, 0, stream>>>(dst, row_start);
  cast_h<<<(N_NODES * HIDDEN / 8 + 255) / 256, 256, 0, stream>>>(h_in, hb0);
  cast_w<<<(12 * 16384 + 255) / 256, 256, 0, stream>>>(Wq, Wk, Wv, wtb);
  cast_wout<<<(48 * 128 + 255) / 256, 256, 0, stream>>>(Wout, wout_t);

  unsigned short* hcur = hb0;
  unsigned short* hnext = hb1;
  for (int l = 0; l < N_LAYERS; ++l) {
    gemm_qkv_mfma<<<dim3(313, 3), 256, 0, stream>>>(
        hcur, wtb, bq + (size_t)l * HIDDEN, bk + (size_t)l * HIDDEN, bv + (size_t)l * HIDDEN,
        q, k, v, l);
    edge_fused<<<N_NODES / 4, 256, 0, stream>>>(q, k, v, src, row_start, hnext);
    unsigned short* tmp = hcur; hcur = hnext; hnext = tmp;
  }
  out_head_mfma<<<313, 256, 0, stream>>>(hcur, wout_t, bout, out);
}

// Round 5
// 321.234 us; speedup vs baseline: 2.3398x; 1.0044x over previous
//
#include <hip/hip_runtime.h>
#include <math.h>

#define N_NODES 40000
#define N_EDGES 640000
#define HIDDEN 128
#define N_LAYERS 4
#define N_CLASSES 40
#define SCALING 0.08838834764831845f

typedef __attribute__((ext_vector_type(8))) short short8;
typedef __attribute__((ext_vector_type(4))) float floatx4;

static __device__ __forceinline__ float b2f(unsigned short u) {
  return __uint_as_float(((unsigned)u) << 16);
}
static __device__ __forceinline__ unsigned short f2b(float f) {
  unsigned u = __float_as_uint(f);
  u += 0x7fff + ((u >> 16) & 1);   // round-to-nearest-even
  return (unsigned short)(u >> 16);
}

// ---------------- CSR build: row_start[i] = lower_bound(dst, i) ----------------
__global__ void build_csr(const int* __restrict__ dst, int* __restrict__ row_start) {
  int i = blockIdx.x * blockDim.x + threadIdx.x;
  if (i > N_NODES) return;
  int lo = 0, hi = N_EDGES;
  while (lo < hi) {
    int mid = (lo + hi) >> 1;
    if (dst[mid] < i) lo = mid + 1; else hi = mid;
  }
  row_start[i] = lo;
}

// ---------------- cast h (f32 -> bf16), 8 elems/thread -------------------------
__global__ __launch_bounds__(256) void cast_h(const float* __restrict__ in,
                                              unsigned short* __restrict__ out) {
  int i = blockIdx.x * 256 + threadIdx.x;
  if (i >= N_NODES * HIDDEN / 8) return;
  const float4* p = (const float4*)in + (size_t)i * 2;
  float4 a = p[0], b = p[1];
  union { unsigned short us[8]; uint4 v; } o;
  o.us[0] = f2b(a.x); o.us[1] = f2b(a.y); o.us[2] = f2b(a.z); o.us[3] = f2b(a.w);
  o.us[4] = f2b(b.x); o.us[5] = f2b(b.y); o.us[6] = f2b(b.z); o.us[7] = f2b(b.w);
  ((uint4*)out)[i] = o.v;
}

// ---------------- cast + transpose weights: wtb[l*3+m][n][k] = W[l][k][n] ------
__global__ __launch_bounds__(256) void cast_w(const float* __restrict__ Wq,
                                              const float* __restrict__ Wk,
                                              const float* __restrict__ Wv,
                                              unsigned short* __restrict__ wtb) {
  int idx = blockIdx.x * 256 + threadIdx.x;   // 12*16384 total
  if (idx >= 12 * 16384) return;
  int mat = idx >> 14;
  int rem = idx & 16383;
  int n = rem >> 7, kk = rem & 127;
  int l = mat / 3, m = mat % 3;
  const float* W = (m == 0) ? Wq : (m == 1) ? Wk : Wv;
  float val = W[(size_t)l * 16384 + (size_t)kk * 128 + n];
  wtb[(size_t)mat * 16384 + (size_t)n * 128 + kk] = f2b(val);
}

// ---------------- cast + transpose + pad Wout: wout_t[48][128] -----------------
__global__ __launch_bounds__(256) void cast_wout(const float* __restrict__ Wout,
                                                 unsigned short* __restrict__ wout_t) {
  int idx = blockIdx.x * 256 + threadIdx.x;   // 48*128 = 6144
  if (idx >= 48 * 128) return;
  int n = idx >> 7, kk = idx & 127;
  float val = (n < N_CLASSES) ? Wout[(size_t)kk * N_CLASSES + n] : 0.f;
  wout_t[idx] = f2b(val);
}

// ---------------- QKV GEMM via MFMA bf16, swapped operands ---------------------
// D[dim][node]: A-operand = Wt rows (dims), B-operand = h rows (nodes).
// q -> q[node][128]; k -> kv[node][0..128); v -> kv[node][128..256).
__global__ __launch_bounds__(256) void gemm_qkv_mfma(
    const unsigned short* __restrict__ A,     // 40000x128 bf16
    const unsigned short* __restrict__ wtb,   // 12 x [n][k] bf16
    const float* __restrict__ bq, const float* __restrict__ bk, const float* __restrict__ bv,
    unsigned short* __restrict__ q, unsigned short* __restrict__ kv,
    int layer)
{
  int mat = blockIdx.y;
  const unsigned short* Wt = wtb + ((size_t)(layer * 3 + mat) << 14);
  const float* bias; unsigned short* C; float scale; int cstride;
  if (mat == 0)      { bias = bq; C = q;        scale = SCALING; cstride = 128; }
  else if (mat == 1) { bias = bk; C = kv;       scale = 1.0f;    cstride = 256; }
  else               { bias = bv; C = kv + 128; scale = 1.0f;    cstride = 256; }

  const int wid = threadIdx.x >> 6, lane = threadIdx.x & 63;
  const int r = lane & 15, kg = lane >> 4;
  const int row_base = blockIdx.x * 128 + wid * 32;

  int ar0 = row_base + r;      if (ar0 > N_NODES - 1) ar0 = N_NODES - 1;
  int ar1 = row_base + 16 + r; if (ar1 > N_NODES - 1) ar1 = N_NODES - 1;

  // h fragments (B-operand): loaded once, reused across all 8 dim-frags
  short8 hf[2][4];
  #pragma unroll
  for (int kc = 0; kc < 4; ++kc) {
    hf[0][kc] = *(const short8*)(A + (size_t)ar0 * 128 + kc * 32 + kg * 8);
    hf[1][kc] = *(const short8*)(A + (size_t)ar1 * 128 + kc * 32 + kg * 8);
  }

  floatx4 acc[8][2];
  #pragma unroll
  for (int df = 0; df < 8; ++df) {
    acc[df][0] = (floatx4){0.f, 0.f, 0.f, 0.f};
    acc[df][1] = (floatx4){0.f, 0.f, 0.f, 0.f};
  }

  const unsigned short* wp = Wt + (size_t)r * 128 + kg * 8;
  #pragma unroll
  for (int df = 0; df < 8; ++df) {
    #pragma unroll
    for (int kc = 0; kc < 4; ++kc) {
      short8 wf = *(const short8*)(wp + df * 2048 + kc * 32);
      acc[df][0] = __builtin_amdgcn_mfma_f32_16x16x32_bf16(wf, hf[0][kc], acc[df][0], 0, 0, 0);
      acc[df][1] = __builtin_amdgcn_mfma_f32_16x16x32_bf16(wf, hf[1][kc], acc[df][1], 0, 0, 0);
    }
  }

  // D layout: col(lane&15) = node, row((lane>>4)*4+g) = dim_local
  #pragma unroll
  for (int df = 0; df < 8; ++df) {
    float4 b4 = *(const float4*)&bias[df * 16 + kg * 4];
    #pragma unroll
    for (int f = 0; f < 2; ++f) {
      int node = row_base + f * 16 + r;
      if (node < N_NODES) {
        union { unsigned short us[4]; uint2 u2; } o;
        o.us[0] = f2b((acc[df][f][0] + b4.x) * scale);
        o.us[1] = f2b((acc[df][f][1] + b4.y) * scale);
        o.us[2] = f2b((acc[df][f][2] + b4.z) * scale);
        o.us[3] = f2b((acc[df][f][3] + b4.w) * scale);
        *(uint2*)(C + (size_t)node * cstride + df * 16 + kg * 4) = o.u2;
      }
    }
  }
}

// ---------------- fused edge attention: SDDMM + softmax + SpMM -----------------
// One wave per dst node; each 16-lane subgroup owns one edge end-to-end.
// Depth-2 software pipeline: 2 groups (8 edges) in compute, 2 groups prefetched.
__global__ __launch_bounds__(256) void edge_fused(
    const unsigned short* __restrict__ q, const unsigned short* __restrict__ kv,
    const int* __restrict__ src, const int* __restrict__ row_start,
    unsigned short* __restrict__ hout)
{
  const int lane = threadIdx.x & 63;
  const int node = blockIdx.x * 4 + (threadIdx.x >> 6);   // 40000 % 4 == 0
  const int sg = lane >> 4, sl = lane & 15;

  short8 qf = *(const short8*)(q + (size_t)node * 128 + sl * 8);
  float qd[8];
  #pragma unroll
  for (int j = 0; j < 8; ++j) qd[j] = b2f((unsigned short)qf[j]);

  const int r0 = row_start[node], r1 = row_start[node + 1];

  float acc[8] = {0.f, 0.f, 0.f, 0.f, 0.f, 0.f, 0.f, 0.f};
  float ws = 0.f;

#define LOADG(VLD, KF, VF, C)                                          \
  {                                                                     \
    int e_ = (C) + sg;                                                  \
    VLD = e_ < r1;                                                      \
    int s_ = VLD ? src[e_] : 0;                                         \
    const unsigned short* p_ = kv + ((size_t)s_ << 8) + sl * 8;         \
    KF = *(const short8*)p_;                                            \
    VF = *(const short8*)(p_ + 128);                                    \
  }

#define COMPG(VLD, KF, VF)                                             \
  {                                                                     \
    float d_ = 0.f;                                                     \
    _Pragma("unroll")                                                   \
    for (int j = 0; j < 8; ++j) d_ += qd[j] * b2f((unsigned short)KF[j]); \
    d_ += __shfl_xor(d_, 1, 64);                                        \
    d_ += __shfl_xor(d_, 2, 64);                                        \
    d_ += __shfl_xor(d_, 4, 64);                                        \
    d_ += __shfl_xor(d_, 8, 64);                                        \
    float w_ = VLD ? __expf(d_) : 0.f;                                  \
    ws += w_;                                                           \
    _Pragma("unroll")                                                   \
    for (int j = 0; j < 8; ++j) acc[j] += w_ * b2f((unsigned short)VF[j]); \
  }

  bool vA, vB;
  short8 kA, fA, kB, fB;
  LOADG(vA, kA, fA, r0);
  LOADG(vB, kB, fB, r0 + 4);

  for (int c = r0; c < r1; c += 8) {
    bool vC, vD;
    short8 kC, fC, kD, fD;
    LOADG(vC, kC, fC, c + 8);
    LOADG(vD, kD, fD, c + 12);
    COMPG(vA, kA, fA);
    COMPG(vB, kB, fB);
    vA = vC; kA = kC; fA = fC;
    vB = vD; kB = kD; fB = fD;
  }

#undef LOADG
#undef COMPG

  // combine the 4 subgroups (same dim mapping across sg)
  #pragma unroll
  for (int off = 16; off <= 32; off <<= 1) {
    ws += __shfl_xor(ws, off, 64);
    #pragma unroll
    for (int j = 0; j < 8; ++j) acc[j] += __shfl_xor(acc[j], off, 64);
  }

  if (sg == 0) {
    float inv = (ws > 1e-20f) ? 1.0f / ws : 0.0f;
    union { unsigned short us[8]; uint4 u4; } o;
    #pragma unroll
    for (int j = 0; j < 8; ++j) o.us[j] = f2b(acc[j] * inv);
    *(uint4*)(hout + (size_t)node * 128 + sl * 8) = o.u4;
  }
}

// ---------------- output head via MFMA: logits + log_softmax -------------------
// grid 313 x 256 thr; wave = 32 nodes x 48 classes (40 valid).
__global__ __launch_bounds__(256) void out_head_mfma(
    const unsigned short* __restrict__ h, const unsigned short* __restrict__ wout_t,
    const float* __restrict__ bout, float* __restrict__ out)
{
  const int wid = threadIdx.x >> 6, lane = threadIdx.x & 63;
  const int r = lane & 15, kg = lane >> 4;
  const int row_base = blockIdx.x * 128 + wid * 32;

  int ar0 = row_base + r;      if (ar0 > N_NODES - 1) ar0 = N_NODES - 1;
  int ar1 = row_base + 16 + r; if (ar1 > N_NODES - 1) ar1 = N_NODES - 1;

  floatx4 acc[2][3];
  #pragma unroll
  for (int f = 0; f < 2; ++f)
    #pragma unroll
    for (int n = 0; n < 3; ++n) acc[f][n] = (floatx4){0.f, 0.f, 0.f, 0.f};

  const unsigned short* a0p = h + (size_t)ar0 * 128 + kg * 8;
  const unsigned short* a1p = h + (size_t)ar1 * 128 + kg * 8;
  const unsigned short* bp  = wout_t + (size_t)r * 128 + kg * 8;

  #pragma unroll
  for (int kc = 0; kc < 128; kc += 32) {
    short8 a0 = *(const short8*)(a0p + kc);
    short8 a1 = *(const short8*)(a1p + kc);
    #pragma unroll
    for (int n = 0; n < 3; ++n) {
      short8 b = *(const short8*)(bp + n * 2048 + kc);
      acc[0][n] = __builtin_amdgcn_mfma_f32_16x16x32_bf16(a0, b, acc[0][n], 0, 0, 0);
      acc[1][n] = __builtin_amdgcn_mfma_f32_16x16x32_bf16(a1, b, acc[1][n], 0, 0, 0);
    }
  }

  float bn0 = bout[r];
  float bn1 = bout[16 + r];
  float bn2 = (r < 8) ? bout[32 + r] : 0.f;

  #pragma unroll
  for (int f = 0; f < 2; ++f) {
    #pragma unroll
    for (int g = 0; g < 4; ++g) {
      int row = row_base + f * 16 + kg * 4 + g;
      float l0 = acc[f][0][g] + bn0;
      float l1 = acc[f][1][g] + bn1;
      float l2 = acc[f][2][g] + bn2;          // valid only if r < 8
      float m = fmaxf(l0, l1);
      if (r < 8) m = fmaxf(m, l2);
      #pragma unroll
      for (int off = 8; off >= 1; off >>= 1) m = fmaxf(m, __shfl_xor(m, off, 64));
      float s = __expf(l0 - m) + __expf(l1 - m) + ((r < 8) ? __expf(l2 - m) : 0.f);
      #pragma unroll
      for (int off = 8; off >= 1; off >>= 1) s += __shfl_xor(s, off, 64);
      float lse = m + logf(s);
      if (row < N_NODES) {
        float* op = out + (size_t)row * N_CLASSES;
        op[r]      = l0 - lse;
        op[16 + r] = l1 - lse;
        if (r < 8) op[32 + r] = l2 - lse;
      }
    }
  }
}

extern "C" void kernel_launch(void* const* d_in, const int* in_sizes, int n_in,
                              void* d_out, int out_size, void* d_ws, size_t ws_size,
                              hipStream_t stream) {
  const float* h_in = (const float*)d_in[0];
  const int*   src  = (const int*)d_in[1];
  const int*   dst  = (const int*)d_in[2];
  const float* Wq   = (const float*)d_in[3];
  const float* bq   = (const float*)d_in[4];
  const float* Wk   = (const float*)d_in[5];
  const float* bk   = (const float*)d_in[6];
  const float* Wv   = (const float*)d_in[7];
  const float* bv   = (const float*)d_in[8];
  const float* Wout = (const float*)d_in[9];
  const float* bout = (const float*)d_in[10];
  float* out = (float*)d_out;

  char* ws = (char*)d_ws;
  size_t off = 0;
  auto alloc = [&](size_t bytes) -> void* {
    void* p = ws + off;
    off += (bytes + 255) & ~(size_t)255;
    return p;
  };
  int*            row_start = (int*)           alloc((size_t)(N_NODES + 1) * sizeof(int));
  unsigned short* hb0       = (unsigned short*)alloc((size_t)N_NODES * HIDDEN * 2);
  unsigned short* hb1       = (unsigned short*)alloc((size_t)N_NODES * HIDDEN * 2);
  unsigned short* q         = (unsigned short*)alloc((size_t)N_NODES * HIDDEN * 2);
  unsigned short* kv        = (unsigned short*)alloc((size_t)N_NODES * 256 * 2);
  unsigned short* wtb       = (unsigned short*)alloc((size_t)12 * 16384 * 2);
  unsigned short* wout_t    = (unsigned short*)alloc((size_t)48 * 128 * 2);

  build_csr<<<(N_NODES + 256) / 256, 256, 0, stream>>>(dst, row_start);
  cast_h<<<(N_NODES * HIDDEN / 8 + 255) / 256, 256, 0, stream>>>(h_in, hb0);
  cast_w<<<(12 * 16384 + 255) / 256, 256, 0, stream>>>(Wq, Wk, Wv, wtb);
  cast_wout<<<(48 * 128 + 255) / 256, 256, 0, stream>>>(Wout, wout_t);

  unsigned short* hcur = hb0;
  unsigned short* hnext = hb1;
  for (int l = 0; l < N_LAYERS; ++l) {
    gemm_qkv_mfma<<<dim3(313, 3), 256, 0, stream>>>(
        hcur, wtb, bq + (size_t)l * HIDDEN, bk + (size_t)l * HIDDEN, bv + (size_t)l * HIDDEN,
        q, kv, l);
    edge_fused<<<N_NODES / 4, 256, 0, stream>>>(q, kv, src, row_start, hnext);
    unsigned short* tmp = hcur; hcur = hnext; hnext = tmp;
  }
  out_head_mfma<<<313, 256, 0, stream>>>(hcur, wout_t, bout, out);
}

// Round 6
// 287.521 us; speedup vs baseline: 2.6141x; 1.1173x over previous
//
#include <hip/hip_runtime.h>
#include <math.h>

#define N_NODES 40000
#define N_EDGES 640000
#define HIDDEN 128
#define N_LAYERS 4
#define N_CLASSES 40
#define SCALING 0.08838834764831845f

typedef __attribute__((ext_vector_type(8))) short short8;
typedef __attribute__((ext_vector_type(4))) float floatx4;

static __device__ __forceinline__ float b2f(unsigned short u) {
  return __uint_as_float(((unsigned)u) << 16);
}
static __device__ __forceinline__ unsigned short f2b(float f) {
  unsigned u = __float_as_uint(f);
  u += 0x7fff + ((u >> 16) & 1);   // round-to-nearest-even
  return (unsigned short)(u >> 16);
}

// ---------------- CSR build: row_start[i] = lower_bound(dst, i) ----------------
__global__ void build_csr(const int* __restrict__ dst, int* __restrict__ row_start) {
  int i = blockIdx.x * blockDim.x + threadIdx.x;
  if (i > N_NODES) return;
  int lo = 0, hi = N_EDGES;
  while (lo < hi) {
    int mid = (lo + hi) >> 1;
    if (dst[mid] < i) lo = mid + 1; else hi = mid;
  }
  row_start[i] = lo;
}

// ---------------- cast h (f32 -> bf16), 8 elems/thread -------------------------
__global__ __launch_bounds__(256) void cast_h(const float* __restrict__ in,
                                              unsigned short* __restrict__ out) {
  int i = blockIdx.x * 256 + threadIdx.x;
  if (i >= N_NODES * HIDDEN / 8) return;
  const float4* p = (const float4*)in + (size_t)i * 2;
  float4 a = p[0], b = p[1];
  union { unsigned short us[8]; uint4 v; } o;
  o.us[0] = f2b(a.x); o.us[1] = f2b(a.y); o.us[2] = f2b(a.z); o.us[3] = f2b(a.w);
  o.us[4] = f2b(b.x); o.us[5] = f2b(b.y); o.us[6] = f2b(b.z); o.us[7] = f2b(b.w);
  ((uint4*)out)[i] = o.v;
}

// ---------------- M precompute: mts[l][t'][t] = SCALING * <Wq[l][t,:], Wk[l][t',:]>
// Also bqk[l][t'] = SCALING * <bq[l,:], Wk[l][t',:]>  (exact score folding;
// the dst-constant q.bk term cancels in softmax).
__global__ __launch_bounds__(256) void prep_m(const float* __restrict__ Wq,
                                              const float* __restrict__ Wk,
                                              const float* __restrict__ bq,
                                              unsigned short* __restrict__ mts,
                                              float* __restrict__ bqk) {
  int idx = blockIdx.x * 256 + threadIdx.x;   // 4*16384
  if (idx >= N_LAYERS * 16384) return;
  int l = idx >> 14;
  int rem = idx & 16383;
  int tp = rem >> 7, t = rem & 127;
  const float* wq = Wq + (size_t)l * 16384 + (size_t)t * 128;   // row t of Wq[l]
  const float* wk = Wk + (size_t)l * 16384 + (size_t)tp * 128;  // row t' of Wk[l]
  float acc = 0.f;
  #pragma unroll 4
  for (int j = 0; j < 128; ++j) acc += wq[j] * wk[j];
  mts[(size_t)l * 16384 + (size_t)tp * 128 + t] = f2b(acc * SCALING);
  if (t == 0) {
    const float* bqv = bq + (size_t)l * 128;
    float b = 0.f;
    #pragma unroll 4
    for (int j = 0; j < 128; ++j) b += bqv[j] * wk[j];
    bqk[(size_t)l * 128 + tp] = b * SCALING;
  }
}

// ---------------- cast + transpose Wv: wvt[l][d][k] = Wv[l][k][d] --------------
__global__ __launch_bounds__(256) void cast_wv(const float* __restrict__ Wv,
                                               unsigned short* __restrict__ wvt) {
  int idx = blockIdx.x * 256 + threadIdx.x;   // 4*16384
  if (idx >= N_LAYERS * 16384) return;
  int l = idx >> 14;
  int rem = idx & 16383;
  int d = rem >> 7, kk = rem & 127;
  wvt[(size_t)l * 16384 + (size_t)d * 128 + kk] =
      f2b(Wv[(size_t)l * 16384 + (size_t)kk * 128 + d]);
}

// ---------------- cast + transpose + pad Wout: wout_t[48][128] -----------------
__global__ __launch_bounds__(256) void cast_wout(const float* __restrict__ Wout,
                                                 unsigned short* __restrict__ wout_t) {
  int idx = blockIdx.x * 256 + threadIdx.x;   // 48*128 = 6144
  if (idx >= 48 * 128) return;
  int n = idx >> 7, kk = idx & 127;
  float val = (n < N_CLASSES) ? Wout[(size_t)kk * N_CLASSES + n] : 0.f;
  wout_t[idx] = f2b(val);
}

// ---------------- node GEMM via MFMA bf16, swapped operands --------------------
// C[node][128] = bf16( A[node][:] @ Wt^T + bias ), Wt is [out_dim][in_dim] bf16.
// grid 313, 256 thr = 4 waves x 32 rows.
__global__ __launch_bounds__(256) void gemm_node(
    const unsigned short* __restrict__ A,     // 40000x128 bf16
    const unsigned short* __restrict__ Wt,    // [128][128] bf16, out-major
    const float* __restrict__ bias,           // [128] f32
    unsigned short* __restrict__ C)
{
  const int wid = threadIdx.x >> 6, lane = threadIdx.x & 63;
  const int r = lane & 15, kg = lane >> 4;
  const int row_base = blockIdx.x * 128 + wid * 32;

  int ar0 = row_base + r;      if (ar0 > N_NODES - 1) ar0 = N_NODES - 1;
  int ar1 = row_base + 16 + r; if (ar1 > N_NODES - 1) ar1 = N_NODES - 1;

  short8 hf[2][4];
  #pragma unroll
  for (int kc = 0; kc < 4; ++kc) {
    hf[0][kc] = *(const short8*)(A + (size_t)ar0 * 128 + kc * 32 + kg * 8);
    hf[1][kc] = *(const short8*)(A + (size_t)ar1 * 128 + kc * 32 + kg * 8);
  }

  floatx4 acc[8][2];
  #pragma unroll
  for (int df = 0; df < 8; ++df) {
    acc[df][0] = (floatx4){0.f, 0.f, 0.f, 0.f};
    acc[df][1] = (floatx4){0.f, 0.f, 0.f, 0.f};
  }

  const unsigned short* wp = Wt + (size_t)r * 128 + kg * 8;
  #pragma unroll
  for (int df = 0; df < 8; ++df) {
    #pragma unroll
    for (int kc = 0; kc < 4; ++kc) {
      short8 wf = *(const short8*)(wp + df * 2048 + kc * 32);
      acc[df][0] = __builtin_amdgcn_mfma_f32_16x16x32_bf16(wf, hf[0][kc], acc[df][0], 0, 0, 0);
      acc[df][1] = __builtin_amdgcn_mfma_f32_16x16x32_bf16(wf, hf[1][kc], acc[df][1], 0, 0, 0);
    }
  }

  // D layout: col(lane&15) = node, row((lane>>4)*4+g) = dim_local
  #pragma unroll
  for (int df = 0; df < 8; ++df) {
    float4 b4 = *(const float4*)&bias[df * 16 + kg * 4];
    #pragma unroll
    for (int f = 0; f < 2; ++f) {
      int node = row_base + f * 16 + r;
      if (node < N_NODES) {
        union { unsigned short us[4]; uint2 u2; } o;
        o.us[0] = f2b(acc[df][f][0] + b4.x);
        o.us[1] = f2b(acc[df][f][1] + b4.y);
        o.us[2] = f2b(acc[df][f][2] + b4.z);
        o.us[3] = f2b(acc[df][f][3] + b4.w);
        *(uint2*)(C + (size_t)node * 128 + df * 16 + kg * 4) = o.u2;
      }
    }
  }
}

// ---------------- fused edge attention: score + softmax + h-aggregate ----------
// score_e = qm[dst] . h[src]; g[i] = sum_e softmax(score) * h[src_e].
// One wave per dst node; each 16-lane subgroup owns one edge; the single
// gathered h-row feeds BOTH the dot and the accumulate. Depth-2 pipeline.
__global__ __launch_bounds__(256) void edge_fused(
    const unsigned short* __restrict__ qm, const unsigned short* __restrict__ h,
    const int* __restrict__ src, const int* __restrict__ row_start,
    unsigned short* __restrict__ g)
{
  const int lane = threadIdx.x & 63;
  const int node = blockIdx.x * 4 + (threadIdx.x >> 6);   // 40000 % 4 == 0
  const int sg = lane >> 4, sl = lane & 15;

  short8 qf = *(const short8*)(qm + (size_t)node * 128 + sl * 8);
  float qd[8];
  #pragma unroll
  for (int j = 0; j < 8; ++j) qd[j] = b2f((unsigned short)qf[j]);

  const int r0 = row_start[node], r1 = row_start[node + 1];

  float acc[8] = {0.f, 0.f, 0.f, 0.f, 0.f, 0.f, 0.f, 0.f};
  float ws = 0.f;

#define LOADG(VLD, HF, C)                                               \
  {                                                                     \
    int e_ = (C) + sg;                                                  \
    VLD = e_ < r1;                                                      \
    int s_ = VLD ? src[e_] : 0;                                         \
    HF = *(const short8*)(h + ((size_t)s_ << 7) + sl * 8);              \
  }

#define COMPG(VLD, HF)                                                  \
  {                                                                     \
    float hd_[8];                                                       \
    _Pragma("unroll")                                                   \
    for (int j = 0; j < 8; ++j) hd_[j] = b2f((unsigned short)HF[j]);    \
    float d_ = 0.f;                                                     \
    _Pragma("unroll")                                                   \
    for (int j = 0; j < 8; ++j) d_ += qd[j] * hd_[j];                   \
    d_ += __shfl_xor(d_, 1, 64);                                        \
    d_ += __shfl_xor(d_, 2, 64);                                        \
    d_ += __shfl_xor(d_, 4, 64);                                        \
    d_ += __shfl_xor(d_, 8, 64);                                        \
    float w_ = VLD ? __expf(d_) : 0.f;                                  \
    ws += w_;                                                           \
    _Pragma("unroll")                                                   \
    for (int j = 0; j < 8; ++j) acc[j] += w_ * hd_[j];                  \
  }

  bool vA, vB;
  short8 hA, hB;
  LOADG(vA, hA, r0);
  LOADG(vB, hB, r0 + 4);

  for (int c = r0; c < r1; c += 8) {
    bool vC, vD;
    short8 hC, hD;
    LOADG(vC, hC, c + 8);
    LOADG(vD, hD, c + 12);
    COMPG(vA, hA);
    COMPG(vB, hB);
    vA = vC; hA = hC;
    vB = vD; hB = hD;
  }

#undef LOADG
#undef COMPG

  // combine the 4 subgroups (same dim mapping across sg)
  #pragma unroll
  for (int off = 16; off <= 32; off <<= 1) {
    ws += __shfl_xor(ws, off, 64);
    #pragma unroll
    for (int j = 0; j < 8; ++j) acc[j] += __shfl_xor(acc[j], off, 64);
  }

  if (sg == 0) {
    float inv = (ws > 1e-20f) ? 1.0f / ws : 0.0f;
    union { unsigned short us[8]; uint4 u4; } o;
    #pragma unroll
    for (int j = 0; j < 8; ++j) o.us[j] = f2b(acc[j] * inv);
    *(uint4*)(g + (size_t)node * 128 + sl * 8) = o.u4;
  }
}

// ---------------- output head via MFMA: logits + log_softmax -------------------
// grid 313 x 256 thr; wave = 32 nodes x 48 classes (40 valid).
__global__ __launch_bounds__(256) void out_head_mfma(
    const unsigned short* __restrict__ h, const unsigned short* __restrict__ wout_t,
    const float* __restrict__ bout, float* __restrict__ out)
{
  const int wid = threadIdx.x >> 6, lane = threadIdx.x & 63;
  const int r = lane & 15, kg = lane >> 4;
  const int row_base = blockIdx.x * 128 + wid * 32;

  int ar0 = row_base + r;      if (ar0 > N_NODES - 1) ar0 = N_NODES - 1;
  int ar1 = row_base + 16 + r; if (ar1 > N_NODES - 1) ar1 = N_NODES - 1;

  floatx4 acc[2][3];
  #pragma unroll
  for (int f = 0; f < 2; ++f)
    #pragma unroll
    for (int n = 0; n < 3; ++n) acc[f][n] = (floatx4){0.f, 0.f, 0.f, 0.f};

  const unsigned short* a0p = h + (size_t)ar0 * 128 + kg * 8;
  const unsigned short* a1p = h + (size_t)ar1 * 128 + kg * 8;
  const unsigned short* bp  = wout_t + (size_t)r * 128 + kg * 8;

  #pragma unroll
  for (int kc = 0; kc < 128; kc += 32) {
    short8 a0 = *(const short8*)(a0p + kc);
    short8 a1 = *(const short8*)(a1p + kc);
    #pragma unroll
    for (int n = 0; n < 3; ++n) {
      short8 b = *(const short8*)(bp + n * 2048 + kc);
      acc[0][n] = __builtin_amdgcn_mfma_f32_16x16x32_bf16(a0, b, acc[0][n], 0, 0, 0);
      acc[1][n] = __builtin_amdgcn_mfma_f32_16x16x32_bf16(a1, b, acc[1][n], 0, 0, 0);
    }
  }

  float bn0 = bout[r];
  float bn1 = bout[16 + r];
  float bn2 = (r < 8) ? bout[32 + r] : 0.f;

  #pragma unroll
  for (int f = 0; f < 2; ++f) {
    #pragma unroll
    for (int g = 0; g < 4; ++g) {
      int row = row_base + f * 16 + kg * 4 + g;
      float l0 = acc[f][0][g] + bn0;
      float l1 = acc[f][1][g] + bn1;
      float l2 = acc[f][2][g] + bn2;          // valid only if r < 8
      float m = fmaxf(l0, l1);
      if (r < 8) m = fmaxf(m, l2);
      #pragma unroll
      for (int off = 8; off >= 1; off >>= 1) m = fmaxf(m, __shfl_xor(m, off, 64));
      float s = __expf(l0 - m) + __expf(l1 - m) + ((r < 8) ? __expf(l2 - m) : 0.f);
      #pragma unroll
      for (int off = 8; off >= 1; off >>= 1) s += __shfl_xor(s, off, 64);
      float lse = m + logf(s);
      if (row < N_NODES) {
        float* op = out + (size_t)row * N_CLASSES;
        op[r]      = l0 - lse;
        op[16 + r] = l1 - lse;
        if (r < 8) op[32 + r] = l2 - lse;
      }
    }
  }
}

extern "C" void kernel_launch(void* const* d_in, const int* in_sizes, int n_in,
                              void* d_out, int out_size, void* d_ws, size_t ws_size,
                              hipStream_t stream) {
  const float* h_in = (const float*)d_in[0];
  const int*   src  = (const int*)d_in[1];
  const int*   dst  = (const int*)d_in[2];
  const float* Wq   = (const float*)d_in[3];
  const float* bq   = (const float*)d_in[4];
  const float* Wk   = (const float*)d_in[5];
  const float* bk   = (const float*)d_in[6];  // cancels in softmax (dst-constant)
  const float* Wv   = (const float*)d_in[7];
  const float* bv   = (const float*)d_in[8];
  const float* Wout = (const float*)d_in[9];
  const float* bout = (const float*)d_in[10];
  float* out = (float*)d_out;
  (void)bk;

  char* ws = (char*)d_ws;
  size_t off = 0;
  auto alloc = [&](size_t bytes) -> void* {
    void* p = ws + off;
    off += (bytes + 255) & ~(size_t)255;
    return p;
  };
  int*            row_start = (int*)           alloc((size_t)(N_NODES + 1) * sizeof(int));
  unsigned short* hb0       = (unsigned short*)alloc((size_t)N_NODES * HIDDEN * 2);
  unsigned short* hb1       = (unsigned short*)alloc((size_t)N_NODES * HIDDEN * 2);
  unsigned short* qm        = (unsigned short*)alloc((size_t)N_NODES * HIDDEN * 2);
  unsigned short* gbuf      = (unsigned short*)alloc((size_t)N_NODES * HIDDEN * 2);
  unsigned short* mts       = (unsigned short*)alloc((size_t)N_LAYERS * 16384 * 2);
  float*          bqk       = (float*)         alloc((size_t)N_LAYERS * 128 * sizeof(float));
  unsigned short* wvt       = (unsigned short*)alloc((size_t)N_LAYERS * 16384 * 2);
  unsigned short* wout_t    = (unsigned short*)alloc((size_t)48 * 128 * 2);

  build_csr<<<(N_NODES + 256) / 256, 256, 0, stream>>>(dst, row_start);
  cast_h<<<(N_NODES * HIDDEN / 8 + 255) / 256, 256, 0, stream>>>(h_in, hb0);
  prep_m<<<(N_LAYERS * 16384 + 255) / 256, 256, 0, stream>>>(Wq, Wk, bq, mts, bqk);
  cast_wv<<<(N_LAYERS * 16384 + 255) / 256, 256, 0, stream>>>(Wv, wvt);
  cast_wout<<<(48 * 128 + 255) / 256, 256, 0, stream>>>(Wout, wout_t);

  unsigned short* hcur = hb0;
  unsigned short* hnext = hb1;
  for (int l = 0; l < N_LAYERS; ++l) {
    gemm_node<<<313, 256, 0, stream>>>(
        hcur, mts + (size_t)l * 16384, bqk + (size_t)l * 128, qm);
    edge_fused<<<N_NODES / 4, 256, 0, stream>>>(qm, hcur, src, row_start, gbuf);
    gemm_node<<<313, 256, 0, stream>>>(
        gbuf, wvt + (size_t)l * 16384, bv + (size_t)l * 128, hnext);
    unsigned short* tmp = hcur; hcur = hnext; hnext = tmp;
  }
  out_head_mfma<<<313, 256, 0, stream>>>(hcur, wout_t, bout, out);
}

// Round 7
// 281.238 us; speedup vs baseline: 2.6725x; 1.0223x over previous
//
#include <hip/hip_runtime.h>
#include <math.h>

#define N_NODES 40000
#define N_EDGES 640000
#define HIDDEN 128
#define N_LAYERS 4
#define N_CLASSES 40
#define SCALING 0.08838834764831845f

typedef __attribute__((ext_vector_type(8))) short short8;
typedef __attribute__((ext_vector_type(4))) float floatx4;

static __device__ __forceinline__ float b2f(unsigned short u) {
  return __uint_as_float(((unsigned)u) << 16);
}
static __device__ __forceinline__ unsigned short f2b(float f) {
  unsigned u = __float_as_uint(f);
  u += 0x7fff + ((u >> 16) & 1);   // round-to-nearest-even
  return (unsigned short)(u >> 16);
}

// ---------------- CSR build: row_start[i] = lower_bound(dst, i) ----------------
__global__ void build_csr(const int* __restrict__ dst, int* __restrict__ row_start) {
  int i = blockIdx.x * blockDim.x + threadIdx.x;
  if (i > N_NODES) return;
  int lo = 0, hi = N_EDGES;
  while (lo < hi) {
    int mid = (lo + hi) >> 1;
    if (dst[mid] < i) lo = mid + 1; else hi = mid;
  }
  row_start[i] = lo;
}

// ---------------- cast h (f32 -> bf16), 8 elems/thread -------------------------
__global__ __launch_bounds__(256) void cast_h(const float* __restrict__ in,
                                              unsigned short* __restrict__ out) {
  int i = blockIdx.x * 256 + threadIdx.x;
  if (i >= N_NODES * HIDDEN / 8) return;
  const float4* p = (const float4*)in + (size_t)i * 2;
  float4 a = p[0], b = p[1];
  union { unsigned short us[8]; uint4 v; } o;
  o.us[0] = f2b(a.x); o.us[1] = f2b(a.y); o.us[2] = f2b(a.z); o.us[3] = f2b(a.w);
  o.us[4] = f2b(b.x); o.us[5] = f2b(b.y); o.us[6] = f2b(b.z); o.us[7] = f2b(b.w);
  ((uint4*)out)[i] = o.v;
}

// ---------------- cast all weights to bf16 (+ transposes) ----------------------
// ranges: [0,64K)=Wqb, [64K,128K)=Wkb, [128K,192K)=Wvb (straight casts),
// [192K,240K)=wvt l=0..2 into W2buf[l][0..16384) (transpose),
// [240K,246144)=wout_t[48][128] (transpose + pad).
__global__ __launch_bounds__(256) void cast_all(
    const float* __restrict__ Wq, const float* __restrict__ Wk,
    const float* __restrict__ Wv, const float* __restrict__ Wout,
    unsigned short* __restrict__ Wqb, unsigned short* __restrict__ Wkb,
    unsigned short* __restrict__ Wvb, unsigned short* __restrict__ W2buf,
    unsigned short* __restrict__ wout_t)
{
  int idx = blockIdx.x * 256 + threadIdx.x;
  if (idx < 65536) { Wqb[idx] = f2b(Wq[idx]); return; }
  if (idx < 131072) { int i = idx - 65536; Wkb[i] = f2b(Wk[i]); return; }
  if (idx < 196608) { int i = idx - 131072; Wvb[i] = f2b(Wv[i]); return; }
  if (idx < 245760) {
    int i = idx - 196608;             // l,d,k : wvt[d][k] = Wv[l][k][d]
    int l = i >> 14, rem = i & 16383;
    int d = rem >> 7, kk = rem & 127;
    W2buf[(size_t)l * 32768 + (size_t)d * 128 + kk] =
        f2b(Wv[(size_t)l * 16384 + (size_t)kk * 128 + d]);
    return;
  }
  if (idx < 245760 + 6144) {
    int i = idx - 245760;             // wout_t[c][d] = Wout[d][c], pad c>=40
    int c = i >> 7, d = i & 127;
    wout_t[i] = (c < N_CLASSES) ? f2b(Wout[(size_t)d * N_CLASSES + c]) : 0;
  }
}

// ---------------- small 128x128 MFMA product: out[b][a] = sum_j A[a][j]B[b][j] --
// One workgroup per product. A is [128][128] bf16; B is [n_b<=128][128] bf16.
__device__ __forceinline__ void mm_body(
    const unsigned short* __restrict__ Aop, const unsigned short* __restrict__ Bop,
    unsigned short* __restrict__ outp, int n_b, float scale)
{
  const int wid = threadIdx.x >> 6, lane = threadIdx.x & 63;
  const int r = lane & 15, kg = lane >> 4;
  const int row_base = wid * 32;

  int br0 = row_base + r;      if (br0 > n_b - 1) br0 = n_b - 1;
  int br1 = row_base + 16 + r; if (br1 > n_b - 1) br1 = n_b - 1;

  short8 bf_[2][4];
  #pragma unroll
  for (int kc = 0; kc < 4; ++kc) {
    bf_[0][kc] = *(const short8*)(Bop + (size_t)br0 * 128 + kc * 32 + kg * 8);
    bf_[1][kc] = *(const short8*)(Bop + (size_t)br1 * 128 + kc * 32 + kg * 8);
  }

  floatx4 acc[8][2];
  #pragma unroll
  for (int df = 0; df < 8; ++df) {
    acc[df][0] = (floatx4){0.f, 0.f, 0.f, 0.f};
    acc[df][1] = (floatx4){0.f, 0.f, 0.f, 0.f};
  }

  const unsigned short* ap = Aop + (size_t)r * 128 + kg * 8;
  #pragma unroll
  for (int df = 0; df < 8; ++df) {
    #pragma unroll
    for (int kc = 0; kc < 4; ++kc) {
      short8 af = *(const short8*)(ap + df * 2048 + kc * 32);
      acc[df][0] = __builtin_amdgcn_mfma_f32_16x16x32_bf16(af, bf_[0][kc], acc[df][0], 0, 0, 0);
      acc[df][1] = __builtin_amdgcn_mfma_f32_16x16x32_bf16(af, bf_[1][kc], acc[df][1], 0, 0, 0);
    }
  }

  #pragma unroll
  for (int df = 0; df < 8; ++df) {
    #pragma unroll
    for (int f = 0; f < 2; ++f) {
      int b = row_base + f * 16 + r;
      if (b < n_b) {
        union { unsigned short us[4]; uint2 u2; } o;
        o.us[0] = f2b(acc[df][f][0] * scale);
        o.us[1] = f2b(acc[df][f][1] * scale);
        o.us[2] = f2b(acc[df][f][2] * scale);
        o.us[3] = f2b(acc[df][f][3] * scale);
        *(uint2*)(outp + (size_t)b * 128 + df * 16 + kg * 4) = o.u2;
      }
    }
  }
}

// stage 1: mts_l[tp][t] = S * sum_o Wq[l][t][o] * Wk[l][tp][o]   (grid 4)
__global__ __launch_bounds__(256) void mm_stage1(
    const unsigned short* __restrict__ Wqb, const unsigned short* __restrict__ Wkb,
    unsigned short* __restrict__ mts)
{
  int l = blockIdx.x;
  mm_body(Wqb + (size_t)l * 16384, Wkb + (size_t)l * 16384,
          mts + (size_t)l * 16384, 128, SCALING);
}

// stage 2: cmb_l (l=1..3) into W2buf[l-1][16384..32768), wout2 (grid 4)
__global__ __launch_bounds__(256) void mm_stage2(
    const unsigned short* __restrict__ mts, const unsigned short* __restrict__ Wvb,
    const unsigned short* __restrict__ wout_t,
    unsigned short* __restrict__ W2buf, unsigned short* __restrict__ wout2)
{
  int job = blockIdx.x;
  if (job < 3) {
    int l = job + 1;  // cmb[tp][k] = sum_t mts_l[tp][t] * Wv[l-1][k][t]
    mm_body(Wvb + (size_t)(l - 1) * 16384, mts + (size_t)l * 16384,
            W2buf + (size_t)(l - 1) * 32768 + 16384, 128, 1.0f);
  } else {
    // wout2[c][k] = sum_d wout_t[c][d] * Wv[3][k][d]
    mm_body(Wvb + (size_t)3 * 16384, wout_t, wout2, 48, 1.0f);
  }
}

// ---------------- folded biases (f32) ------------------------------------------
// bqk0[tp] = S sum_o bq0[o] Wk0[tp][o]
// bias2[l-1][0..128) = bv[l-1]; [128..256): bqm_l = sum_t bv[l-1][t] mts_l[tp][t]
//                                           + S sum_o bq_l[o] Wk_l[tp][o]
// bout2[c] = sum_d bv3[d] Wout[d][c] + bout[c]
__global__ __launch_bounds__(256) void bias_prep(
    const float* __restrict__ bq, const float* __restrict__ Wk,
    const float* __restrict__ bv, const float* __restrict__ Wout,
    const float* __restrict__ bout, const unsigned short* __restrict__ mts,
    float* __restrict__ bqk0, float* __restrict__ bias2, float* __restrict__ bout2)
{
  int idx = blockIdx.x * 256 + threadIdx.x;
  if (idx < 128) {
    int tp = idx;
    const float* wkrow = Wk + (size_t)tp * 128;
    float s = 0.f;
    #pragma unroll 4
    for (int j = 0; j < 128; ++j) s += bq[j] * wkrow[j];
    bqk0[tp] = s * SCALING;
  } else if (idx < 512) {
    int i = idx - 128;
    int l = (i >> 7) + 1, tp = i & 127;
    const unsigned short* mrow = mts + (size_t)l * 16384 + (size_t)tp * 128;
    const float* bvp = bv + (size_t)(l - 1) * 128;
    float s = 0.f;
    #pragma unroll 4
    for (int t = 0; t < 128; ++t) s += bvp[t] * b2f(mrow[t]);
    const float* bqp = bq + (size_t)l * 128;
    const float* wkrow = Wk + (size_t)l * 16384 + (size_t)tp * 128;
    float s2 = 0.f;
    #pragma unroll 4
    for (int j = 0; j < 128; ++j) s2 += bqp[j] * wkrow[j];
    bias2[(size_t)(l - 1) * 256 + 128 + tp] = s + s2 * SCALING;
  } else if (idx < 896) {
    int i = idx - 512;
    int l = (i >> 7) + 1, d = i & 127;
    bias2[(size_t)(l - 1) * 256 + d] = bv[(size_t)(l - 1) * 128 + d];
  } else if (idx < 944) {
    int c = idx - 896;
    float s = 0.f;
    #pragma unroll 4
    for (int d = 0; d < 128; ++d) s += bv[3 * 128 + d] * Wout[(size_t)d * N_CLASSES + c];
    bout2[c] = s + bout[c];
  }
}

// ---------------- node GEMM via MFMA bf16 (single 128-wide output) -------------
__global__ __launch_bounds__(256) void gemm_node(
    const unsigned short* __restrict__ A,     // 40000x128 bf16
    const unsigned short* __restrict__ Wt,    // [128][128] bf16, out-major
    const float* __restrict__ bias,           // [128] f32
    unsigned short* __restrict__ C)
{
  const int wid = threadIdx.x >> 6, lane = threadIdx.x & 63;
  const int r = lane & 15, kg = lane >> 4;
  const int row_base = blockIdx.x * 128 + wid * 32;

  int ar0 = row_base + r;      if (ar0 > N_NODES - 1) ar0 = N_NODES - 1;
  int ar1 = row_base + 16 + r; if (ar1 > N_NODES - 1) ar1 = N_NODES - 1;

  short8 hf[2][4];
  #pragma unroll
  for (int kc = 0; kc < 4; ++kc) {
    hf[0][kc] = *(const short8*)(A + (size_t)ar0 * 128 + kc * 32 + kg * 8);
    hf[1][kc] = *(const short8*)(A + (size_t)ar1 * 128 + kc * 32 + kg * 8);
  }

  floatx4 acc[8][2];
  #pragma unroll
  for (int df = 0; df < 8; ++df) {
    acc[df][0] = (floatx4){0.f, 0.f, 0.f, 0.f};
    acc[df][1] = (floatx4){0.f, 0.f, 0.f, 0.f};
  }

  const unsigned short* wp = Wt + (size_t)r * 128 + kg * 8;
  #pragma unroll
  for (int df = 0; df < 8; ++df) {
    #pragma unroll
    for (int kc = 0; kc < 4; ++kc) {
      short8 wf = *(const short8*)(wp + df * 2048 + kc * 32);
      acc[df][0] = __builtin_amdgcn_mfma_f32_16x16x32_bf16(wf, hf[0][kc], acc[df][0], 0, 0, 0);
      acc[df][1] = __builtin_amdgcn_mfma_f32_16x16x32_bf16(wf, hf[1][kc], acc[df][1], 0, 0, 0);
    }
  }

  #pragma unroll
  for (int df = 0; df < 8; ++df) {
    float4 b4 = *(const float4*)&bias[df * 16 + kg * 4];
    #pragma unroll
    for (int f = 0; f < 2; ++f) {
      int node = row_base + f * 16 + r;
      if (node < N_NODES) {
        union { unsigned short us[4]; uint2 u2; } o;
        o.us[0] = f2b(acc[df][f][0] + b4.x);
        o.us[1] = f2b(acc[df][f][1] + b4.y);
        o.us[2] = f2b(acc[df][f][2] + b4.z);
        o.us[3] = f2b(acc[df][f][3] + b4.w);
        *(uint2*)(C + (size_t)node * 128 + df * 16 + kg * 4) = o.u2;
      }
    }
  }
}

// ---------------- dual GEMM: HQ[node][0..128)=h_l, [128..256)=qm_l -------------
// A-fragments loaded ONCE, two weight halves W2=[256][128], bias2=[256].
__global__ __launch_bounds__(256) void gemm_dual(
    const unsigned short* __restrict__ A,     // g, 40000x128 bf16
    const unsigned short* __restrict__ W2,    // [256][128] bf16
    const float* __restrict__ bias2,          // [256] f32
    unsigned short* __restrict__ HQ)          // 40000x256 bf16
{
  const int wid = threadIdx.x >> 6, lane = threadIdx.x & 63;
  const int r = lane & 15, kg = lane >> 4;
  const int row_base = blockIdx.x * 128 + wid * 32;

  int ar0 = row_base + r;      if (ar0 > N_NODES - 1) ar0 = N_NODES - 1;
  int ar1 = row_base + 16 + r; if (ar1 > N_NODES - 1) ar1 = N_NODES - 1;

  short8 hf[2][4];
  #pragma unroll
  for (int kc = 0; kc < 4; ++kc) {
    hf[0][kc] = *(const short8*)(A + (size_t)ar0 * 128 + kc * 32 + kg * 8);
    hf[1][kc] = *(const short8*)(A + (size_t)ar1 * 128 + kc * 32 + kg * 8);
  }

  #pragma unroll
  for (int half = 0; half < 2; ++half) {
    floatx4 acc[8][2];
    #pragma unroll
    for (int df = 0; df < 8; ++df) {
      acc[df][0] = (floatx4){0.f, 0.f, 0.f, 0.f};
      acc[df][1] = (floatx4){0.f, 0.f, 0.f, 0.f};
    }
    const unsigned short* wp = W2 + half * 16384 + (size_t)r * 128 + kg * 8;
    #pragma unroll
    for (int df = 0; df < 8; ++df) {
      #pragma unroll
      for (int kc = 0; kc < 4; ++kc) {
        short8 wf = *(const short8*)(wp + df * 2048 + kc * 32);
        acc[df][0] = __builtin_amdgcn_mfma_f32_16x16x32_bf16(wf, hf[0][kc], acc[df][0], 0, 0, 0);
        acc[df][1] = __builtin_amdgcn_mfma_f32_16x16x32_bf16(wf, hf[1][kc], acc[df][1], 0, 0, 0);
      }
    }
    #pragma unroll
    for (int df = 0; df < 8; ++df) {
      float4 b4 = *(const float4*)&bias2[half * 128 + df * 16 + kg * 4];
      #pragma unroll
      for (int f = 0; f < 2; ++f) {
        int node = row_base + f * 16 + r;
        if (node < N_NODES) {
          union { unsigned short us[4]; uint2 u2; } o;
          o.us[0] = f2b(acc[df][f][0] + b4.x);
          o.us[1] = f2b(acc[df][f][1] + b4.y);
          o.us[2] = f2b(acc[df][f][2] + b4.z);
          o.us[3] = f2b(acc[df][f][3] + b4.w);
          *(uint2*)(HQ + (size_t)node * 256 + half * 128 + df * 16 + kg * 4) = o.u2;
        }
      }
    }
  }
}

// ---------------- fused edge attention: score + softmax + h-aggregate ----------
// score_e = qm[dst] . h[src]; g[i] = sum_e softmax(score) * h[src_e].
// Row strides passed as template shifts (qm: 1<<QSH shorts, h: 1<<HSH shorts).
template<int QSH, int HSH>
__global__ __launch_bounds__(256) void edge_fused(
    const unsigned short* __restrict__ qm, const unsigned short* __restrict__ h,
    const int* __restrict__ src, const int* __restrict__ row_start,
    unsigned short* __restrict__ g)
{
  const int lane = threadIdx.x & 63;
  const int node = blockIdx.x * 4 + (threadIdx.x >> 6);   // 40000 % 4 == 0
  const int sg = lane >> 4, sl = lane & 15;

  short8 qf = *(const short8*)(qm + ((size_t)node << QSH) + sl * 8);
  float qd[8];
  #pragma unroll
  for (int j = 0; j < 8; ++j) qd[j] = b2f((unsigned short)qf[j]);

  const int r0 = row_start[node], r1 = row_start[node + 1];

  float acc[8] = {0.f, 0.f, 0.f, 0.f, 0.f, 0.f, 0.f, 0.f};
  float ws = 0.f;

#define LOADG(VLD, HF, C)                                               \
  {                                                                     \
    int e_ = (C) + sg;                                                  \
    VLD = e_ < r1;                                                      \
    int s_ = VLD ? src[e_] : 0;                                         \
    HF = *(const short8*)(h + ((size_t)s_ << HSH) + sl * 8);            \
  }

#define COMPG(VLD, HF)                                                  \
  {                                                                     \
    float hd_[8];                                                       \
    _Pragma("unroll")                                                   \
    for (int j = 0; j < 8; ++j) hd_[j] = b2f((unsigned short)HF[j]);    \
    float d_ = 0.f;                                                     \
    _Pragma("unroll")                                                   \
    for (int j = 0; j < 8; ++j) d_ += qd[j] * hd_[j];                   \
    d_ += __shfl_xor(d_, 1, 64);                                        \
    d_ += __shfl_xor(d_, 2, 64);                                        \
    d_ += __shfl_xor(d_, 4, 64);                                        \
    d_ += __shfl_xor(d_, 8, 64);                                        \
    float w_ = VLD ? __expf(d_) : 0.f;                                  \
    ws += w_;                                                           \
    _Pragma("unroll")                                                   \
    for (int j = 0; j < 8; ++j) acc[j] += w_ * hd_[j];                  \
  }

  bool vA, vB;
  short8 hA, hB;
  LOADG(vA, hA, r0);
  LOADG(vB, hB, r0 + 4);

  for (int c = r0; c < r1; c += 8) {
    bool vC, vD;
    short8 hC, hD;
    LOADG(vC, hC, c + 8);
    LOADG(vD, hD, c + 12);
    COMPG(vA, hA);
    COMPG(vB, hB);
    vA = vC; hA = hC;
    vB = vD; hB = hD;
  }

#undef LOADG
#undef COMPG

  #pragma unroll
  for (int off = 16; off <= 32; off <<= 1) {
    ws += __shfl_xor(ws, off, 64);
    #pragma unroll
    for (int j = 0; j < 8; ++j) acc[j] += __shfl_xor(acc[j], off, 64);
  }

  if (sg == 0) {
    float inv = (ws > 1e-20f) ? 1.0f / ws : 0.0f;
    union { unsigned short us[8]; uint4 u4; } o;
    #pragma unroll
    for (int j = 0; j < 8; ++j) o.us[j] = f2b(acc[j] * inv);
    *(uint4*)(g + (size_t)node * 128 + sl * 8) = o.u4;
  }
}

// ---------------- output head via MFMA: logits + log_softmax -------------------
// grid 313 x 256 thr; wave = 32 nodes x 48 classes (40 valid).
__global__ __launch_bounds__(256) void out_head_mfma(
    const unsigned short* __restrict__ h, const unsigned short* __restrict__ wout_t,
    const float* __restrict__ bout, float* __restrict__ out)
{
  const int wid = threadIdx.x >> 6, lane = threadIdx.x & 63;
  const int r = lane & 15, kg = lane >> 4;
  const int row_base = blockIdx.x * 128 + wid * 32;

  int ar0 = row_base + r;      if (ar0 > N_NODES - 1) ar0 = N_NODES - 1;
  int ar1 = row_base + 16 + r; if (ar1 > N_NODES - 1) ar1 = N_NODES - 1;

  floatx4 acc[2][3];
  #pragma unroll
  for (int f = 0; f < 2; ++f)
    #pragma unroll
    for (int n = 0; n < 3; ++n) acc[f][n] = (floatx4){0.f, 0.f, 0.f, 0.f};

  const unsigned short* a0p = h + (size_t)ar0 * 128 + kg * 8;
  const unsigned short* a1p = h + (size_t)ar1 * 128 + kg * 8;
  const unsigned short* bp  = wout_t + (size_t)r * 128 + kg * 8;

  #pragma unroll
  for (int kc = 0; kc < 128; kc += 32) {
    short8 a0 = *(const short8*)(a0p + kc);
    short8 a1 = *(const short8*)(a1p + kc);
    #pragma unroll
    for (int n = 0; n < 3; ++n) {
      short8 b = *(const short8*)(bp + n * 2048 + kc);
      acc[0][n] = __builtin_amdgcn_mfma_f32_16x16x32_bf16(a0, b, acc[0][n], 0, 0, 0);
      acc[1][n] = __builtin_amdgcn_mfma_f32_16x16x32_bf16(a1, b, acc[1][n], 0, 0, 0);
    }
  }

  float bn0 = bout[r];
  float bn1 = bout[16 + r];
  float bn2 = (r < 8) ? bout[32 + r] : 0.f;

  #pragma unroll
  for (int f = 0; f < 2; ++f) {
    #pragma unroll
    for (int g = 0; g < 4; ++g) {
      int row = row_base + f * 16 + kg * 4 + g;
      float l0 = acc[f][0][g] + bn0;
      float l1 = acc[f][1][g] + bn1;
      float l2 = acc[f][2][g] + bn2;          // valid only if r < 8
      float m = fmaxf(l0, l1);
      if (r < 8) m = fmaxf(m, l2);
      #pragma unroll
      for (int off = 8; off >= 1; off >>= 1) m = fmaxf(m, __shfl_xor(m, off, 64));
      float s = __expf(l0 - m) + __expf(l1 - m) + ((r < 8) ? __expf(l2 - m) : 0.f);
      #pragma unroll
      for (int off = 8; off >= 1; off >>= 1) s += __shfl_xor(s, off, 64);
      float lse = m + logf(s);
      if (row < N_NODES) {
        float* op = out + (size_t)row * N_CLASSES;
        op[r]      = l0 - lse;
        op[16 + r] = l1 - lse;
        if (r < 8) op[32 + r] = l2 - lse;
      }
    }
  }
}

extern "C" void kernel_launch(void* const* d_in, const int* in_sizes, int n_in,
                              void* d_out, int out_size, void* d_ws, size_t ws_size,
                              hipStream_t stream) {
  const float* h_in = (const float*)d_in[0];
  const int*   src  = (const int*)d_in[1];
  const int*   dst  = (const int*)d_in[2];
  const float* Wq   = (const float*)d_in[3];
  const float* bq   = (const float*)d_in[4];
  const float* Wk   = (const float*)d_in[5];
  const float* bk   = (const float*)d_in[6];  // cancels in softmax (dst-constant)
  const float* Wv   = (const float*)d_in[7];
  const float* bv   = (const float*)d_in[8];
  const float* Wout = (const float*)d_in[9];
  const float* bout = (const float*)d_in[10];
  float* out = (float*)d_out;
  (void)bk;

  char* ws = (char*)d_ws;
  size_t off = 0;
  auto alloc = [&](size_t bytes) -> void* {
    void* p = ws + off;
    off += (bytes + 255) & ~(size_t)255;
    return p;
  };
  int*            row_start = (int*)           alloc((size_t)(N_NODES + 1) * sizeof(int));
  unsigned short* hb0       = (unsigned short*)alloc((size_t)N_NODES * 128 * 2);
  unsigned short* qm0       = (unsigned short*)alloc((size_t)N_NODES * 128 * 2);
  unsigned short* g0        = (unsigned short*)alloc((size_t)N_NODES * 128 * 2);
  unsigned short* g1        = (unsigned short*)alloc((size_t)N_NODES * 128 * 2);
  unsigned short* hq        = (unsigned short*)alloc((size_t)N_NODES * 256 * 2);
  unsigned short* mts       = (unsigned short*)alloc((size_t)4 * 16384 * 2);
  unsigned short* W2buf     = (unsigned short*)alloc((size_t)3 * 32768 * 2);
  unsigned short* wout2     = (unsigned short*)alloc((size_t)48 * 128 * 2);
  unsigned short* Wqb       = (unsigned short*)alloc((size_t)4 * 16384 * 2);
  unsigned short* Wkb       = (unsigned short*)alloc((size_t)4 * 16384 * 2);
  unsigned short* Wvb       = (unsigned short*)alloc((size_t)4 * 16384 * 2);
  unsigned short* wout_t    = (unsigned short*)alloc((size_t)48 * 128 * 2);
  float*          bqk0      = (float*)         alloc(128 * sizeof(float));
  float*          bias2     = (float*)         alloc(3 * 256 * sizeof(float));
  float*          bout2     = (float*)         alloc(48 * sizeof(float));

  cast_all<<<(251904 + 255) / 256, 256, 0, stream>>>(
      Wq, Wk, Wv, Wout, Wqb, Wkb, Wvb, W2buf, wout_t);
  cast_h<<<(N_NODES * 128 / 8 + 255) / 256, 256, 0, stream>>>(h_in, hb0);
  build_csr<<<(N_NODES + 256) / 256, 256, 0, stream>>>(dst, row_start);
  mm_stage1<<<4, 256, 0, stream>>>(Wqb, Wkb, mts);
  mm_stage2<<<4, 256, 0, stream>>>(mts, Wvb, wout_t, W2buf, wout2);
  bias_prep<<<4, 256, 0, stream>>>(bq, Wk, bv, Wout, bout, mts, bqk0, bias2, bout2);

  // layer 0
  gemm_node<<<313, 256, 0, stream>>>(hb0, mts, bqk0, qm0);
  edge_fused<7, 7><<<N_NODES / 4, 256, 0, stream>>>(qm0, hb0, src, row_start, g0);
  // layers 1..3 (folded transitions)
  unsigned short* gprev = g0;
  unsigned short* gnext = g1;
  for (int l = 1; l < N_LAYERS; ++l) {
    gemm_dual<<<313, 256, 0, stream>>>(
        gprev, W2buf + (size_t)(l - 1) * 32768, bias2 + (size_t)(l - 1) * 256, hq);
    edge_fused<8, 8><<<N_NODES / 4, 256, 0, stream>>>(hq + 128, hq, src, row_start, gnext);
    unsigned short* tmp = gprev; gprev = gnext; gnext = tmp;
  }
  // head folded with Wv_3
  out_head_mfma<<<313, 256, 0, stream>>>(gprev, wout2, bout2, out);
}

// Round 8
// 275.963 us; speedup vs baseline: 2.7236x; 1.0191x over previous
//
#include <hip/hip_runtime.h>
#include <math.h>

#define N_NODES 40000
#define N_EDGES 640000
#define HIDDEN 128
#define N_LAYERS 4
#define N_CLASSES 40
#define SCALING 0.08838834764831845f

typedef __attribute__((ext_vector_type(8))) short short8;
typedef __attribute__((ext_vector_type(4))) float floatx4;

static __device__ __forceinline__ float b2f(unsigned short u) {
  return __uint_as_float(((unsigned)u) << 16);
}
static __device__ __forceinline__ unsigned short f2b(float f) {
  unsigned u = __float_as_uint(f);
  u += 0x7fff + ((u >> 16) & 1);   // round-to-nearest-even
  return (unsigned short)(u >> 16);
}

// ---------------- fused setup: cast_h + weight casts/transposes + CSR ----------
// idx ranges: [0,640K) cast_h; [640K, 640K+251904) weight casts; tail build_csr.
__global__ __launch_bounds__(256) void setup_all(
    const float* __restrict__ h_in, const int* __restrict__ dst,
    const float* __restrict__ Wq, const float* __restrict__ Wk,
    const float* __restrict__ Wv, const float* __restrict__ Wout,
    unsigned short* __restrict__ hb0, int* __restrict__ row_start,
    unsigned short* __restrict__ Wqb, unsigned short* __restrict__ Wkb,
    unsigned short* __restrict__ Wvb, unsigned short* __restrict__ W2buf,
    unsigned short* __restrict__ wout_t)
{
  int idx = blockIdx.x * 256 + threadIdx.x;
  if (idx < 640000) {
    const float4* p = (const float4*)h_in + (size_t)idx * 2;
    float4 a = p[0], b = p[1];
    union { unsigned short us[8]; uint4 v; } o;
    o.us[0] = f2b(a.x); o.us[1] = f2b(a.y); o.us[2] = f2b(a.z); o.us[3] = f2b(a.w);
    o.us[4] = f2b(b.x); o.us[5] = f2b(b.y); o.us[6] = f2b(b.z); o.us[7] = f2b(b.w);
    ((uint4*)hb0)[idx] = o.v;
    return;
  }
  int j = idx - 640000;
  if (j < 65536) { Wqb[j] = f2b(Wq[j]); return; }
  if (j < 131072) { int i = j - 65536; Wkb[i] = f2b(Wk[i]); return; }
  if (j < 196608) { int i = j - 131072; Wvb[i] = f2b(Wv[i]); return; }
  if (j < 245760) {
    int i = j - 196608;               // wvt[l][d][k] = Wv[l][k][d]
    int l = i >> 14, rem = i & 16383;
    int d = rem >> 7, kk = rem & 127;
    W2buf[(size_t)l * 32768 + (size_t)d * 128 + kk] =
        f2b(Wv[(size_t)l * 16384 + (size_t)kk * 128 + d]);
    return;
  }
  if (j < 251904) {
    int i = j - 245760;               // wout_t[c][d] = Wout[d][c], pad c>=40
    int c = i >> 7, d = i & 127;
    wout_t[i] = (c < N_CLASSES) ? f2b(Wout[(size_t)d * N_CLASSES + c]) : 0;
    return;
  }
  int c = j - 251904;
  if (c <= N_NODES) {                 // row_start[c] = lower_bound(dst, c)
    int lo = 0, hi = N_EDGES;
    while (lo < hi) {
      int mid = (lo + hi) >> 1;
      if (dst[mid] < c) lo = mid + 1; else hi = mid;
    }
    row_start[c] = lo;
  }
}

// ---------------- small 128x128 MFMA product: out[b][a] = sum_j A[a][j]B[b][j] --
__device__ __forceinline__ void mm_body(
    const unsigned short* __restrict__ Aop, const unsigned short* __restrict__ Bop,
    unsigned short* __restrict__ outp, int n_b, float scale)
{
  const int wid = threadIdx.x >> 6, lane = threadIdx.x & 63;
  const int r = lane & 15, kg = lane >> 4;
  const int row_base = wid * 32;

  int br0 = row_base + r;      if (br0 > n_b - 1) br0 = n_b - 1;
  int br1 = row_base + 16 + r; if (br1 > n_b - 1) br1 = n_b - 1;

  short8 bf_[2][4];
  #pragma unroll
  for (int kc = 0; kc < 4; ++kc) {
    bf_[0][kc] = *(const short8*)(Bop + (size_t)br0 * 128 + kc * 32 + kg * 8);
    bf_[1][kc] = *(const short8*)(Bop + (size_t)br1 * 128 + kc * 32 + kg * 8);
  }

  floatx4 acc[8][2];
  #pragma unroll
  for (int df = 0; df < 8; ++df) {
    acc[df][0] = (floatx4){0.f, 0.f, 0.f, 0.f};
    acc[df][1] = (floatx4){0.f, 0.f, 0.f, 0.f};
  }

  const unsigned short* ap = Aop + (size_t)r * 128 + kg * 8;
  #pragma unroll
  for (int df = 0; df < 8; ++df) {
    #pragma unroll
    for (int kc = 0; kc < 4; ++kc) {
      short8 af = *(const short8*)(ap + df * 2048 + kc * 32);
      acc[df][0] = __builtin_amdgcn_mfma_f32_16x16x32_bf16(af, bf_[0][kc], acc[df][0], 0, 0, 0);
      acc[df][1] = __builtin_amdgcn_mfma_f32_16x16x32_bf16(af, bf_[1][kc], acc[df][1], 0, 0, 0);
    }
  }

  #pragma unroll
  for (int df = 0; df < 8; ++df) {
    #pragma unroll
    for (int f = 0; f < 2; ++f) {
      int b = row_base + f * 16 + r;
      if (b < n_b) {
        union { unsigned short us[4]; uint2 u2; } o;
        o.us[0] = f2b(acc[df][f][0] * scale);
        o.us[1] = f2b(acc[df][f][1] * scale);
        o.us[2] = f2b(acc[df][f][2] * scale);
        o.us[3] = f2b(acc[df][f][3] * scale);
        *(uint2*)(outp + (size_t)b * 128 + df * 16 + kg * 4) = o.u2;
      }
    }
  }
}

// stage 1: mts_l[tp][t] = S * sum_o Wq[l][t][o] * Wk[l][tp][o]   (grid 4)
__global__ __launch_bounds__(256) void mm_stage1(
    const unsigned short* __restrict__ Wqb, const unsigned short* __restrict__ Wkb,
    unsigned short* __restrict__ mts)
{
  int l = blockIdx.x;
  mm_body(Wqb + (size_t)l * 16384, Wkb + (size_t)l * 16384,
          mts + (size_t)l * 16384, 128, SCALING);
}

// stage 2 + folded biases (grid 8: blocks 0-3 weight products, 4-7 biases)
__global__ __launch_bounds__(256) void stage2_bias(
    const unsigned short* __restrict__ mts, const unsigned short* __restrict__ Wvb,
    const unsigned short* __restrict__ wout_t,
    unsigned short* __restrict__ W2buf, unsigned short* __restrict__ wout2,
    const float* __restrict__ bq, const float* __restrict__ Wk,
    const float* __restrict__ bv, const float* __restrict__ Wout,
    const float* __restrict__ bout,
    float* __restrict__ bqk0, float* __restrict__ bias2, float* __restrict__ bout2)
{
  int job = blockIdx.x;
  if (job < 3) {
    int l = job + 1;  // cmb[tp][k] = sum_t mts_l[tp][t] * Wv[l-1][k][t]
    mm_body(Wvb + (size_t)(l - 1) * 16384, mts + (size_t)l * 16384,
            W2buf + (size_t)(l - 1) * 32768 + 16384, 128, 1.0f);
    return;
  }
  if (job == 3) {
    // wout2[c][k] = sum_d wout_t[c][d] * Wv[3][k][d]
    mm_body(Wvb + (size_t)3 * 16384, wout_t, wout2, 48, 1.0f);
    return;
  }
  int idx = (job - 4) * 256 + threadIdx.x;   // [0,1024)
  if (idx < 128) {
    int tp = idx;
    const float* wkrow = Wk + (size_t)tp * 128;
    float s = 0.f;
    #pragma unroll 4
    for (int j = 0; j < 128; ++j) s += bq[j] * wkrow[j];
    bqk0[tp] = s * SCALING;
  } else if (idx < 512) {
    int i = idx - 128;
    int l = (i >> 7) + 1, tp = i & 127;
    const unsigned short* mrow = mts + (size_t)l * 16384 + (size_t)tp * 128;
    const float* bvp = bv + (size_t)(l - 1) * 128;
    float s = 0.f;
    #pragma unroll 4
    for (int t = 0; t < 128; ++t) s += bvp[t] * b2f(mrow[t]);
    const float* bqp = bq + (size_t)l * 128;
    const float* wkrow = Wk + (size_t)l * 16384 + (size_t)tp * 128;
    float s2 = 0.f;
    #pragma unroll 4
    for (int j = 0; j < 128; ++j) s2 += bqp[j] * wkrow[j];
    bias2[(size_t)(l - 1) * 256 + 128 + tp] = s + s2 * SCALING;
  } else if (idx < 896) {
    int i = idx - 512;
    int l = (i >> 7) + 1, d = i & 127;
    bias2[(size_t)(l - 1) * 256 + d] = bv[(size_t)(l - 1) * 128 + d];
  } else if (idx < 944) {
    int c = idx - 896;
    float s = 0.f;
    #pragma unroll 4
    for (int d = 0; d < 128; ++d) s += bv[3 * 128 + d] * Wout[(size_t)d * N_CLASSES + c];
    bout2[c] = s + bout[c];
  }
}

// ---------------- node GEMM via MFMA bf16, occupancy-tuned ---------------------
// 16 rows x NCOLS/2 cols per wave; grid 1250 (40000 = 1250 x 32, no clamps).
// wid: bit0 = column half, bit1 = row sub-block.
template<int NCOLS>
__global__ __launch_bounds__(256) void gemm_qn(
    const unsigned short* __restrict__ A,     // 40000x128 bf16
    const unsigned short* __restrict__ Wt,    // [NCOLS][128] bf16, out-major
    const float* __restrict__ bias,           // [NCOLS] f32
    unsigned short* __restrict__ C)           // 40000xNCOLS bf16
{
  constexpr int HALF = NCOLS / 2;
  constexpr int NDF = HALF / 16;
  const int wid = threadIdx.x >> 6, lane = threadIdx.x & 63;
  const int r = lane & 15, kg = lane >> 4;
  const int colhalf = wid & 1, rowsub = wid >> 1;
  const int colbase = colhalf * HALF;
  const int row = blockIdx.x * 32 + rowsub * 16 + r;   // always < 40000

  short8 hf[4];
  #pragma unroll
  for (int kc = 0; kc < 4; ++kc)
    hf[kc] = *(const short8*)(A + (size_t)row * 128 + kc * 32 + kg * 8);

  floatx4 acc[NDF];
  #pragma unroll
  for (int df = 0; df < NDF; ++df) acc[df] = (floatx4){0.f, 0.f, 0.f, 0.f};

  const unsigned short* wp = Wt + (size_t)(colbase + r) * 128 + kg * 8;
  #pragma unroll
  for (int df = 0; df < NDF; ++df) {
    #pragma unroll
    for (int kc = 0; kc < 4; ++kc) {
      short8 wf = *(const short8*)(wp + df * 2048 + kc * 32);
      acc[df] = __builtin_amdgcn_mfma_f32_16x16x32_bf16(wf, hf[kc], acc[df], 0, 0, 0);
    }
  }

  // D: col(lane&15) = node, row(kg*4+g) = dim_local
  #pragma unroll
  for (int df = 0; df < NDF; ++df) {
    float4 b4 = *(const float4*)&bias[colbase + df * 16 + kg * 4];
    union { unsigned short us[4]; uint2 u2; } o;
    o.us[0] = f2b(acc[df][0] + b4.x);
    o.us[1] = f2b(acc[df][1] + b4.y);
    o.us[2] = f2b(acc[df][2] + b4.z);
    o.us[3] = f2b(acc[df][3] + b4.w);
    *(uint2*)(C + (size_t)row * NCOLS + colbase + df * 16 + kg * 4) = o.u2;
  }
}

// ---------------- fused edge attention: score + softmax + h-aggregate ----------
// score_e = qm[dst] . h[src]; g[i] = sum_e softmax(score) * h[src_e].
template<int QSH, int HSH>
__global__ __launch_bounds__(256) void edge_fused(
    const unsigned short* __restrict__ qm, const unsigned short* __restrict__ h,
    const int* __restrict__ src, const int* __restrict__ row_start,
    unsigned short* __restrict__ g)
{
  const int lane = threadIdx.x & 63;
  const int node = blockIdx.x * 4 + (threadIdx.x >> 6);   // 40000 % 4 == 0
  const int sg = lane >> 4, sl = lane & 15;

  short8 qf = *(const short8*)(qm + ((size_t)node << QSH) + sl * 8);
  float qd[8];
  #pragma unroll
  for (int j = 0; j < 8; ++j) qd[j] = b2f((unsigned short)qf[j]);

  const int r0 = row_start[node], r1 = row_start[node + 1];

  float acc[8] = {0.f, 0.f, 0.f, 0.f, 0.f, 0.f, 0.f, 0.f};
  float ws = 0.f;

#define LOADG(VLD, HF, C)                                               \
  {                                                                     \
    int e_ = (C) + sg;                                                  \
    VLD = e_ < r1;                                                      \
    int s_ = VLD ? src[e_] : 0;                                         \
    HF = *(const short8*)(h + ((size_t)s_ << HSH) + sl * 8);            \
  }

#define COMPG(VLD, HF)                                                  \
  {                                                                     \
    float hd_[8];                                                       \
    _Pragma("unroll")                                                   \
    for (int j = 0; j < 8; ++j) hd_[j] = b2f((unsigned short)HF[j]);    \
    float d_ = 0.f;                                                     \
    _Pragma("unroll")                                                   \
    for (int j = 0; j < 8; ++j) d_ += qd[j] * hd_[j];                   \
    d_ += __shfl_xor(d_, 1, 64);                                        \
    d_ += __shfl_xor(d_, 2, 64);                                        \
    d_ += __shfl_xor(d_, 4, 64);                                        \
    d_ += __shfl_xor(d_, 8, 64);                                        \
    float w_ = VLD ? __expf(d_) : 0.f;                                  \
    ws += w_;                                                           \
    _Pragma("unroll")                                                   \
    for (int j = 0; j < 8; ++j) acc[j] += w_ * hd_[j];                  \
  }

  bool vA, vB;
  short8 hA, hB;
  LOADG(vA, hA, r0);
  LOADG(vB, hB, r0 + 4);

  for (int c = r0; c < r1; c += 8) {
    bool vC, vD;
    short8 hC, hD;
    LOADG(vC, hC, c + 8);
    LOADG(vD, hD, c + 12);
    COMPG(vA, hA);
    COMPG(vB, hB);
    vA = vC; hA = hC;
    vB = vD; hB = hD;
  }

#undef LOADG
#undef COMPG

  #pragma unroll
  for (int off = 16; off <= 32; off <<= 1) {
    ws += __shfl_xor(ws, off, 64);
    #pragma unroll
    for (int j = 0; j < 8; ++j) acc[j] += __shfl_xor(acc[j], off, 64);
  }

  if (sg == 0) {
    float inv = (ws > 1e-20f) ? 1.0f / ws : 0.0f;
    union { unsigned short us[8]; uint4 u4; } o;
    #pragma unroll
    for (int j = 0; j < 8; ++j) o.us[j] = f2b(acc[j] * inv);
    *(uint4*)(g + (size_t)node * 128 + sl * 8) = o.u4;
  }
}

// ---------------- output head via MFMA: logits + log_softmax -------------------
// grid 625, 16 rows/wave (40000 = 625 x 64, no clamps).
__global__ __launch_bounds__(256) void out_head_mfma(
    const unsigned short* __restrict__ h, const unsigned short* __restrict__ wout_t,
    const float* __restrict__ bout, float* __restrict__ out)
{
  const int wid = threadIdx.x >> 6, lane = threadIdx.x & 63;
  const int r = lane & 15, kg = lane >> 4;
  const int row_base = blockIdx.x * 64 + wid * 16;
  const int ar = row_base + r;

  floatx4 acc[3];
  #pragma unroll
  for (int n = 0; n < 3; ++n) acc[n] = (floatx4){0.f, 0.f, 0.f, 0.f};

  const unsigned short* ap = h + (size_t)ar * 128 + kg * 8;
  const unsigned short* bp = wout_t + (size_t)r * 128 + kg * 8;

  #pragma unroll
  for (int kc = 0; kc < 128; kc += 32) {
    short8 a0 = *(const short8*)(ap + kc);
    #pragma unroll
    for (int n = 0; n < 3; ++n) {
      short8 b = *(const short8*)(bp + n * 2048 + kc);
      acc[n] = __builtin_amdgcn_mfma_f32_16x16x32_bf16(a0, b, acc[n], 0, 0, 0);
    }
  }

  float bn0 = bout[r];
  float bn1 = bout[16 + r];
  float bn2 = (r < 8) ? bout[32 + r] : 0.f;

  #pragma unroll
  for (int g = 0; g < 4; ++g) {
    int row = row_base + kg * 4 + g;
    float l0 = acc[0][g] + bn0;
    float l1 = acc[1][g] + bn1;
    float l2 = acc[2][g] + bn2;          // valid only if r < 8
    float m = fmaxf(l0, l1);
    if (r < 8) m = fmaxf(m, l2);
    #pragma unroll
    for (int off = 8; off >= 1; off >>= 1) m = fmaxf(m, __shfl_xor(m, off, 64));
    float s = __expf(l0 - m) + __expf(l1 - m) + ((r < 8) ? __expf(l2 - m) : 0.f);
    #pragma unroll
    for (int off = 8; off >= 1; off >>= 1) s += __shfl_xor(s, off, 64);
    float lse = m + logf(s);
    float* op = out + (size_t)row * N_CLASSES;
    op[r]      = l0 - lse;
    op[16 + r] = l1 - lse;
    if (r < 8) op[32 + r] = l2 - lse;
  }
}

extern "C" void kernel_launch(void* const* d_in, const int* in_sizes, int n_in,
                              void* d_out, int out_size, void* d_ws, size_t ws_size,
                              hipStream_t stream) {
  const float* h_in = (const float*)d_in[0];
  const int*   src  = (const int*)d_in[1];
  const int*   dst  = (const int*)d_in[2];
  const float* Wq   = (const float*)d_in[3];
  const float* bq   = (const float*)d_in[4];
  const float* Wk   = (const float*)d_in[5];
  const float* bk   = (const float*)d_in[6];  // cancels in softmax (dst-constant)
  const float* Wv   = (const float*)d_in[7];
  const float* bv   = (const float*)d_in[8];
  const float* Wout = (const float*)d_in[9];
  const float* bout = (const float*)d_in[10];
  float* out = (float*)d_out;
  (void)bk;

  char* ws = (char*)d_ws;
  size_t off = 0;
  auto alloc = [&](size_t bytes) -> void* {
    void* p = ws + off;
    off += (bytes + 255) & ~(size_t)255;
    return p;
  };
  int*            row_start = (int*)           alloc((size_t)(N_NODES + 1) * sizeof(int));
  unsigned short* hb0       = (unsigned short*)alloc((size_t)N_NODES * 128 * 2);
  unsigned short* qm0       = (unsigned short*)alloc((size_t)N_NODES * 128 * 2);
  unsigned short* g0        = (unsigned short*)alloc((size_t)N_NODES * 128 * 2);
  unsigned short* g1        = (unsigned short*)alloc((size_t)N_NODES * 128 * 2);
  unsigned short* hq        = (unsigned short*)alloc((size_t)N_NODES * 256 * 2);
  unsigned short* mts       = (unsigned short*)alloc((size_t)4 * 16384 * 2);
  unsigned short* W2buf     = (unsigned short*)alloc((size_t)3 * 32768 * 2);
  unsigned short* wout2     = (unsigned short*)alloc((size_t)48 * 128 * 2);
  unsigned short* Wqb       = (unsigned short*)alloc((size_t)4 * 16384 * 2);
  unsigned short* Wkb       = (unsigned short*)alloc((size_t)4 * 16384 * 2);
  unsigned short* Wvb       = (unsigned short*)alloc((size_t)4 * 16384 * 2);
  unsigned short* wout_t    = (unsigned short*)alloc((size_t)48 * 128 * 2);
  float*          bqk0      = (float*)         alloc(128 * sizeof(float));
  float*          bias2     = (float*)         alloc(3 * 256 * sizeof(float));
  float*          bout2     = (float*)         alloc(48 * sizeof(float));

  setup_all<<<3641, 256, 0, stream>>>(h_in, dst, Wq, Wk, Wv, Wout,
                                      hb0, row_start, Wqb, Wkb, Wvb, W2buf, wout_t);
  mm_stage1<<<4, 256, 0, stream>>>(Wqb, Wkb, mts);
  stage2_bias<<<8, 256, 0, stream>>>(mts, Wvb, wout_t, W2buf, wout2,
                                     bq, Wk, bv, Wout, bout, bqk0, bias2, bout2);

  // layer 0
  gemm_qn<128><<<1250, 256, 0, stream>>>(hb0, mts, bqk0, qm0);
  edge_fused<7, 7><<<N_NODES / 4, 256, 0, stream>>>(qm0, hb0, src, row_start, g0);
  // layers 1..3 (folded transitions)
  unsigned short* gprev = g0;
  unsigned short* gnext = g1;
  for (int l = 1; l < N_LAYERS; ++l) {
    gemm_qn<256><<<1250, 256, 0, stream>>>(
        gprev, W2buf + (size_t)(l - 1) * 32768, bias2 + (size_t)(l - 1) * 256, hq);
    edge_fused<8, 8><<<N_NODES / 4, 256, 0, stream>>>(hq + 128, hq, src, row_start, gnext);
    unsigned short* tmp = gprev; gprev = gnext; gnext = tmp;
  }
  // head folded with Wv_3
  out_head_mfma<<<625, 256, 0, stream>>>(gprev, wout2, bout2, out);
}

// Round 9
// 251.030 us; speedup vs baseline: 2.9941x; 1.0993x over previous
//
#include <hip/hip_runtime.h>
#include <math.h>

#define N_NODES 40000
#define N_EDGES 640000
#define HIDDEN 128
#define N_LAYERS 4
#define N_CLASSES 40
#define SCALING 0.08838834764831845f

typedef __attribute__((ext_vector_type(8))) short short8;
typedef __attribute__((ext_vector_type(4))) float floatx4;

static __device__ __forceinline__ float b2f(unsigned short u) {
  return __uint_as_float(((unsigned)u) << 16);
}
static __device__ __forceinline__ unsigned short f2b(float f) {
  unsigned u = __float_as_uint(f);
  u += 0x7fff + ((u >> 16) & 1);   // round-to-nearest-even
  return (unsigned short)(u >> 16);
}

// ---------------- fused setup: cast_h + weight casts/transposes + CSR ----------
__global__ __launch_bounds__(256) void setup_all(
    const float* __restrict__ h_in, const int* __restrict__ dst,
    const float* __restrict__ Wq, const float* __restrict__ Wk,
    const float* __restrict__ Wv, const float* __restrict__ Wout,
    unsigned short* __restrict__ hb0, int* __restrict__ row_start,
    unsigned short* __restrict__ Wqb, unsigned short* __restrict__ Wkb,
    unsigned short* __restrict__ Wvb, unsigned short* __restrict__ W2buf,
    unsigned short* __restrict__ wout_t)
{
  int idx = blockIdx.x * 256 + threadIdx.x;
  if (idx < 640000) {
    const float4* p = (const float4*)h_in + (size_t)idx * 2;
    float4 a = p[0], b = p[1];
    union { unsigned short us[8]; uint4 v; } o;
    o.us[0] = f2b(a.x); o.us[1] = f2b(a.y); o.us[2] = f2b(a.z); o.us[3] = f2b(a.w);
    o.us[4] = f2b(b.x); o.us[5] = f2b(b.y); o.us[6] = f2b(b.z); o.us[7] = f2b(b.w);
    ((uint4*)hb0)[idx] = o.v;
    return;
  }
  int j = idx - 640000;
  if (j < 65536) { Wqb[j] = f2b(Wq[j]); return; }
  if (j < 131072) { int i = j - 65536; Wkb[i] = f2b(Wk[i]); return; }
  if (j < 196608) { int i = j - 131072; Wvb[i] = f2b(Wv[i]); return; }
  if (j < 245760) {
    int i = j - 196608;               // wvt[l][d][k] = Wv[l][k][d]
    int l = i >> 14, rem = i & 16383;
    int d = rem >> 7, kk = rem & 127;
    W2buf[(size_t)l * 32768 + (size_t)d * 128 + kk] =
        f2b(Wv[(size_t)l * 16384 + (size_t)kk * 128 + d]);
    return;
  }
  if (j < 251904) {
    int i = j - 245760;               // wout_t[c][d] = Wout[d][c], pad c>=40
    int c = i >> 7, d = i & 127;
    wout_t[i] = (c < N_CLASSES) ? f2b(Wout[(size_t)d * N_CLASSES + c]) : 0;
    return;
  }
  int c = j - 251904;
  if (c <= N_NODES) {                 // row_start[c] = lower_bound(dst, c)
    int lo = 0, hi = N_EDGES;
    while (lo < hi) {
      int mid = (lo + hi) >> 1;
      if (dst[mid] < c) lo = mid + 1; else hi = mid;
    }
    row_start[c] = lo;
  }
}

// ---------------- small 128x128 MFMA product: out[b][a] = sum_j A[a][j]B[b][j] --
__device__ __forceinline__ void mm_body(
    const unsigned short* __restrict__ Aop, const unsigned short* __restrict__ Bop,
    unsigned short* __restrict__ outp, int n_b, float scale)
{
  const int wid = threadIdx.x >> 6, lane = threadIdx.x & 63;
  const int r = lane & 15, kg = lane >> 4;
  const int row_base = wid * 32;

  int br0 = row_base + r;      if (br0 > n_b - 1) br0 = n_b - 1;
  int br1 = row_base + 16 + r; if (br1 > n_b - 1) br1 = n_b - 1;

  short8 bf_[2][4];
  #pragma unroll
  for (int kc = 0; kc < 4; ++kc) {
    bf_[0][kc] = *(const short8*)(Bop + (size_t)br0 * 128 + kc * 32 + kg * 8);
    bf_[1][kc] = *(const short8*)(Bop + (size_t)br1 * 128 + kc * 32 + kg * 8);
  }

  floatx4 acc[8][2];
  #pragma unroll
  for (int df = 0; df < 8; ++df) {
    acc[df][0] = (floatx4){0.f, 0.f, 0.f, 0.f};
    acc[df][1] = (floatx4){0.f, 0.f, 0.f, 0.f};
  }

  const unsigned short* ap = Aop + (size_t)r * 128 + kg * 8;
  #pragma unroll
  for (int df = 0; df < 8; ++df) {
    #pragma unroll
    for (int kc = 0; kc < 4; ++kc) {
      short8 af = *(const short8*)(ap + df * 2048 + kc * 32);
      acc[df][0] = __builtin_amdgcn_mfma_f32_16x16x32_bf16(af, bf_[0][kc], acc[df][0], 0, 0, 0);
      acc[df][1] = __builtin_amdgcn_mfma_f32_16x16x32_bf16(af, bf_[1][kc], acc[df][1], 0, 0, 0);
    }
  }

  #pragma unroll
  for (int df = 0; df < 8; ++df) {
    #pragma unroll
    for (int f = 0; f < 2; ++f) {
      int b = row_base + f * 16 + r;
      if (b < n_b) {
        union { unsigned short us[4]; uint2 u2; } o;
        o.us[0] = f2b(acc[df][f][0] * scale);
        o.us[1] = f2b(acc[df][f][1] * scale);
        o.us[2] = f2b(acc[df][f][2] * scale);
        o.us[3] = f2b(acc[df][f][3] * scale);
        *(uint2*)(outp + (size_t)b * 128 + df * 16 + kg * 4) = o.u2;
      }
    }
  }
}

// stage 1: mts_l[tp][t] = S * sum_o Wq[l][t][o] * Wk[l][tp][o]   (grid 4)
__global__ __launch_bounds__(256) void mm_stage1(
    const unsigned short* __restrict__ Wqb, const unsigned short* __restrict__ Wkb,
    unsigned short* __restrict__ mts)
{
  int l = blockIdx.x;
  mm_body(Wqb + (size_t)l * 16384, Wkb + (size_t)l * 16384,
          mts + (size_t)l * 16384, 128, SCALING);
}

// stage 2 + folded biases (grid 8: blocks 0-3 weight products, 4-7 biases)
__global__ __launch_bounds__(256) void stage2_bias(
    const unsigned short* __restrict__ mts, const unsigned short* __restrict__ Wvb,
    const unsigned short* __restrict__ wout_t,
    unsigned short* __restrict__ W2buf, unsigned short* __restrict__ wout2,
    const float* __restrict__ bq, const float* __restrict__ Wk,
    const float* __restrict__ bv, const float* __restrict__ Wout,
    const float* __restrict__ bout,
    float* __restrict__ bqk0, float* __restrict__ bias2, float* __restrict__ bout2)
{
  int job = blockIdx.x;
  if (job < 3) {
    int l = job + 1;  // cmb[tp][k] = sum_t mts_l[tp][t] * Wv[l-1][k][t]
    mm_body(Wvb + (size_t)(l - 1) * 16384, mts + (size_t)l * 16384,
            W2buf + (size_t)(l - 1) * 32768 + 16384, 128, 1.0f);
    return;
  }
  if (job == 3) {
    mm_body(Wvb + (size_t)3 * 16384, wout_t, wout2, 48, 1.0f);
    return;
  }
  int idx = (job - 4) * 256 + threadIdx.x;   // [0,1024)
  if (idx < 128) {
    int tp = idx;
    const float* wkrow = Wk + (size_t)tp * 128;
    float s = 0.f;
    #pragma unroll 4
    for (int j = 0; j < 128; ++j) s += bq[j] * wkrow[j];
    bqk0[tp] = s * SCALING;
  } else if (idx < 512) {
    int i = idx - 128;
    int l = (i >> 7) + 1, tp = i & 127;
    const unsigned short* mrow = mts + (size_t)l * 16384 + (size_t)tp * 128;
    const float* bvp = bv + (size_t)(l - 1) * 128;
    float s = 0.f;
    #pragma unroll 4
    for (int t = 0; t < 128; ++t) s += bvp[t] * b2f(mrow[t]);
    const float* bqp = bq + (size_t)l * 128;
    const float* wkrow = Wk + (size_t)l * 16384 + (size_t)tp * 128;
    float s2 = 0.f;
    #pragma unroll 4
    for (int j = 0; j < 128; ++j) s2 += bqp[j] * wkrow[j];
    bias2[(size_t)(l - 1) * 256 + 128 + tp] = s + s2 * SCALING;
  } else if (idx < 896) {
    int i = idx - 512;
    int l = (i >> 7) + 1, d = i & 127;
    bias2[(size_t)(l - 1) * 256 + d] = bv[(size_t)(l - 1) * 128 + d];
  } else if (idx < 944) {
    int c = idx - 896;
    float s = 0.f;
    #pragma unroll 4
    for (int d = 0; d < 128; ++d) s += bv[3 * 128 + d] * Wout[(size_t)d * N_CLASSES + c];
    bout2[c] = s + bout[c];
  }
}

// ---------------- node GEMM via MFMA bf16, LDS-staged coalesced epilogue -------
// 16 rows x NCOLS/2 cols per wave; grid 1250. Block writes one CONTIGUOUS
// 32*NCOLS*2-byte run (full cache lines) after staging the tile in LDS.
// LDS XOR swizzle (byte ^= (row&7)<<4) kills the 512B-stride bank conflict.
template<int NCOLS>
__global__ __launch_bounds__(256) void gemm_qn(
    const unsigned short* __restrict__ A,     // 40000x128 bf16
    const unsigned short* __restrict__ Wt,    // [NCOLS][128] bf16, out-major
    const float* __restrict__ bias,           // [NCOLS] f32
    unsigned short* __restrict__ C)           // 40000xNCOLS bf16
{
  constexpr int HALF = NCOLS / 2;
  constexpr int NDF = HALF / 16;
  constexpr int ROWB = NCOLS * 2;           // bytes per output row
  __shared__ __align__(16) unsigned char cs[32 * ROWB];

  const int tid = threadIdx.x;
  const int wid = tid >> 6, lane = tid & 63;
  const int r = lane & 15, kg = lane >> 4;
  const int colhalf = wid & 1, rowsub = wid >> 1;
  const int colbase = colhalf * HALF;
  const int ro = rowsub * 16 + r;           // local row 0..31
  const int row = blockIdx.x * 32 + ro;     // always < 40000

  short8 hf[4];
  #pragma unroll
  for (int kc = 0; kc < 4; ++kc)
    hf[kc] = *(const short8*)(A + (size_t)row * 128 + kc * 32 + kg * 8);

  floatx4 acc[NDF];
  #pragma unroll
  for (int df = 0; df < NDF; ++df) acc[df] = (floatx4){0.f, 0.f, 0.f, 0.f};

  const unsigned short* wp = Wt + (size_t)(colbase + r) * 128 + kg * 8;
  #pragma unroll
  for (int df = 0; df < NDF; ++df) {
    #pragma unroll
    for (int kc = 0; kc < 4; ++kc) {
      short8 wf = *(const short8*)(wp + df * 2048 + kc * 32);
      acc[df] = __builtin_amdgcn_mfma_f32_16x16x32_bf16(wf, hf[kc], acc[df], 0, 0, 0);
    }
  }

  // stage to LDS (D: col(lane&15)=node-row ro, row(kg*4+g)=dim)
  #pragma unroll
  for (int df = 0; df < NDF; ++df) {
    float4 b4 = *(const float4*)&bias[colbase + df * 16 + kg * 4];
    union { unsigned short us[4]; uint2 u2; } o;
    o.us[0] = f2b(acc[df][0] + b4.x);
    o.us[1] = f2b(acc[df][1] + b4.y);
    o.us[2] = f2b(acc[df][2] + b4.z);
    o.us[3] = f2b(acc[df][3] + b4.w);
    int colb = (colbase + df * 16 + kg * 4) * 2;
    *(uint2*)(cs + ro * ROWB + (colb ^ ((ro & 7) << 4))) = o.u2;
  }
  __syncthreads();

  // contiguous block store: 32 rows x ROWB bytes, 16B per lane
  unsigned char* dstb = (unsigned char*)(C + (size_t)blockIdx.x * 32 * NCOLS);
  constexpr int NV = 32 * ROWB / 16;        // uint4 count (1024 / 512)
  #pragma unroll
  for (int i = 0; i < NV / 256; ++i) {
    int byte = (i * 256 + tid) * 16;
    int ro2 = byte / ROWB;
    int colb2 = byte & (ROWB - 1);
    *(uint4*)(dstb + byte) =
        *(const uint4*)(cs + ro2 * ROWB + (colb2 ^ ((ro2 & 7) << 4)));
  }
}

// ---------------- fused edge attention: score + softmax + h-aggregate ----------
// 2 waves per block (one node each): halves block-retire imbalance vs 4 waves.
template<int QSH, int HSH>
__global__ __launch_bounds__(128) void edge_fused(
    const unsigned short* __restrict__ qm, const unsigned short* __restrict__ h,
    const int* __restrict__ src, const int* __restrict__ row_start,
    unsigned short* __restrict__ g)
{
  const int lane = threadIdx.x & 63;
  const int node = blockIdx.x * 2 + (threadIdx.x >> 6);   // 40000 % 2 == 0
  const int sg = lane >> 4, sl = lane & 15;

  short8 qf = *(const short8*)(qm + ((size_t)node << QSH) + sl * 8);
  float qd[8];
  #pragma unroll
  for (int j = 0; j < 8; ++j) qd[j] = b2f((unsigned short)qf[j]);

  const int r0 = row_start[node], r1 = row_start[node + 1];

  float acc[8] = {0.f, 0.f, 0.f, 0.f, 0.f, 0.f, 0.f, 0.f};
  float ws = 0.f;

#define LOADG(VLD, HF, C)                                               \
  {                                                                     \
    int e_ = (C) + sg;                                                  \
    VLD = e_ < r1;                                                      \
    int s_ = VLD ? src[e_] : 0;                                         \
    HF = *(const short8*)(h + ((size_t)s_ << HSH) + sl * 8);            \
  }

#define COMPG(VLD, HF)                                                  \
  {                                                                     \
    float hd_[8];                                                       \
    _Pragma("unroll")                                                   \
    for (int j = 0; j < 8; ++j) hd_[j] = b2f((unsigned short)HF[j]);    \
    float d0_ = 0.f, d1_ = 0.f;                                         \
    _Pragma("unroll")                                                   \
    for (int j = 0; j < 4; ++j) d0_ += qd[j] * hd_[j];                  \
    _Pragma("unroll")                                                   \
    for (int j = 4; j < 8; ++j) d1_ += qd[j] * hd_[j];                  \
    float d_ = d0_ + d1_;                                               \
    d_ += __shfl_xor(d_, 1, 64);                                        \
    d_ += __shfl_xor(d_, 2, 64);                                        \
    d_ += __shfl_xor(d_, 4, 64);                                        \
    d_ += __shfl_xor(d_, 8, 64);                                        \
    float w_ = VLD ? __expf(d_) : 0.f;                                  \
    ws += w_;                                                           \
    _Pragma("unroll")                                                   \
    for (int j = 0; j < 8; ++j) acc[j] += w_ * hd_[j];                  \
  }

  bool vA, vB;
  short8 hA, hB;
  LOADG(vA, hA, r0);
  LOADG(vB, hB, r0 + 4);

  for (int c = r0; c < r1; c += 8) {
    bool vC, vD;
    short8 hC, hD;
    LOADG(vC, hC, c + 8);
    LOADG(vD, hD, c + 12);
    COMPG(vA, hA);
    COMPG(vB, hB);
    vA = vC; hA = hC;
    vB = vD; hB = hD;
  }

#undef LOADG
#undef COMPG

  #pragma unroll
  for (int off = 16; off <= 32; off <<= 1) {
    ws += __shfl_xor(ws, off, 64);
    #pragma unroll
    for (int j = 0; j < 8; ++j) acc[j] += __shfl_xor(acc[j], off, 64);
  }

  if (sg == 0) {
    float inv = (ws > 1e-20f) ? 1.0f / ws : 0.0f;
    union { unsigned short us[8]; uint4 u4; } o;
    #pragma unroll
    for (int j = 0; j < 8; ++j) o.us[j] = f2b(acc[j] * inv);
    *(uint4*)(g + (size_t)node * 128 + sl * 8) = o.u4;
  }
}

// ---------------- output head via MFMA: logits + log_softmax -------------------
// grid 625, 16 rows/wave; LDS-staged contiguous f32 stores (64 rows x 160B).
__global__ __launch_bounds__(256) void out_head_mfma(
    const unsigned short* __restrict__ h, const unsigned short* __restrict__ wout_t,
    const float* __restrict__ bout, float* __restrict__ out)
{
  __shared__ __align__(16) float os[64 * N_CLASSES];   // 10240 B

  const int wid = threadIdx.x >> 6, lane = threadIdx.x & 63;
  const int r = lane & 15, kg = lane >> 4;
  const int row_base = blockIdx.x * 64 + wid * 16;
  const int ar = row_base + r;

  floatx4 acc[3];
  #pragma unroll
  for (int n = 0; n < 3; ++n) acc[n] = (floatx4){0.f, 0.f, 0.f, 0.f};

  const unsigned short* ap = h + (size_t)ar * 128 + kg * 8;
  const unsigned short* bp = wout_t + (size_t)r * 128 + kg * 8;

  #pragma unroll
  for (int kc = 0; kc < 128; kc += 32) {
    short8 a0 = *(const short8*)(ap + kc);
    #pragma unroll
    for (int n = 0; n < 3; ++n) {
      short8 b = *(const short8*)(bp + n * 2048 + kc);
      acc[n] = __builtin_amdgcn_mfma_f32_16x16x32_bf16(a0, b, acc[n], 0, 0, 0);
    }
  }

  float bn0 = bout[r];
  float bn1 = bout[16 + r];
  float bn2 = (r < 8) ? bout[32 + r] : 0.f;

  #pragma unroll
  for (int g = 0; g < 4; ++g) {
    int rl = wid * 16 + kg * 4 + g;          // local row 0..63
    float l0 = acc[0][g] + bn0;
    float l1 = acc[1][g] + bn1;
    float l2 = acc[2][g] + bn2;              // valid only if r < 8
    float m = fmaxf(l0, l1);
    if (r < 8) m = fmaxf(m, l2);
    #pragma unroll
    for (int off = 8; off >= 1; off >>= 1) m = fmaxf(m, __shfl_xor(m, off, 64));
    float s = __expf(l0 - m) + __expf(l1 - m) + ((r < 8) ? __expf(l2 - m) : 0.f);
    #pragma unroll
    for (int off = 8; off >= 1; off >>= 1) s += __shfl_xor(s, off, 64);
    float lse = m + logf(s);
    os[rl * N_CLASSES + r]      = l0 - lse;
    os[rl * N_CLASSES + 16 + r] = l1 - lse;
    if (r < 8) os[rl * N_CLASSES + 32 + r] = l2 - lse;
  }
  __syncthreads();

  // contiguous store: 64 rows x 160B = 10240B (640 uint4)
  float* dstb = out + (size_t)blockIdx.x * 64 * N_CLASSES;
  #pragma unroll
  for (int i = 0; i < 3; ++i) {
    int idx = i * 256 + threadIdx.x;
    if (idx < 640)
      *(uint4*)(dstb + idx * 4) = *(const uint4*)(os + idx * 4);
  }
}

extern "C" void kernel_launch(void* const* d_in, const int* in_sizes, int n_in,
                              void* d_out, int out_size, void* d_ws, size_t ws_size,
                              hipStream_t stream) {
  const float* h_in = (const float*)d_in[0];
  const int*   src  = (const int*)d_in[1];
  const int*   dst  = (const int*)d_in[2];
  const float* Wq   = (const float*)d_in[3];
  const float* bq   = (const float*)d_in[4];
  const float* Wk   = (const float*)d_in[5];
  const float* bk   = (const float*)d_in[6];  // cancels in softmax (dst-constant)
  const float* Wv   = (const float*)d_in[7];
  const float* bv   = (const float*)d_in[8];
  const float* Wout = (const float*)d_in[9];
  const float* bout = (const float*)d_in[10];
  float* out = (float*)d_out;
  (void)bk;

  char* ws = (char*)d_ws;
  size_t off = 0;
  auto alloc = [&](size_t bytes) -> void* {
    void* p = ws + off;
    off += (bytes + 255) & ~(size_t)255;
    return p;
  };
  int*            row_start = (int*)           alloc((size_t)(N_NODES + 1) * sizeof(int));
  unsigned short* hb0       = (unsigned short*)alloc((size_t)N_NODES * 128 * 2);
  unsigned short* qm0       = (unsigned short*)alloc((size_t)N_NODES * 128 * 2);
  unsigned short* g0        = (unsigned short*)alloc((size_t)N_NODES * 128 * 2);
  unsigned short* g1        = (unsigned short*)alloc((size_t)N_NODES * 128 * 2);
  unsigned short* hq        = (unsigned short*)alloc((size_t)N_NODES * 256 * 2);
  unsigned short* mts       = (unsigned short*)alloc((size_t)4 * 16384 * 2);
  unsigned short* W2buf     = (unsigned short*)alloc((size_t)3 * 32768 * 2);
  unsigned short* wout2     = (unsigned short*)alloc((size_t)48 * 128 * 2);
  unsigned short* Wqb       = (unsigned short*)alloc((size_t)4 * 16384 * 2);
  unsigned short* Wkb       = (unsigned short*)alloc((size_t)4 * 16384 * 2);
  unsigned short* Wvb       = (unsigned short*)alloc((size_t)4 * 16384 * 2);
  unsigned short* wout_t    = (unsigned short*)alloc((size_t)48 * 128 * 2);
  float*          bqk0      = (float*)         alloc(128 * sizeof(float));
  float*          bias2     = (float*)         alloc(3 * 256 * sizeof(float));
  float*          bout2     = (float*)         alloc(48 * sizeof(float));

  setup_all<<<3641, 256, 0, stream>>>(h_in, dst, Wq, Wk, Wv, Wout,
                                      hb0, row_start, Wqb, Wkb, Wvb, W2buf, wout_t);
  mm_stage1<<<4, 256, 0, stream>>>(Wqb, Wkb, mts);
  stage2_bias<<<8, 256, 0, stream>>>(mts, Wvb, wout_t, W2buf, wout2,
                                     bq, Wk, bv, Wout, bout, bqk0, bias2, bout2);

  // layer 0
  gemm_qn<128><<<1250, 256, 0, stream>>>(hb0, mts, bqk0, qm0);
  edge_fused<7, 7><<<N_NODES / 2, 128, 0, stream>>>(qm0, hb0, src, row_start, g0);
  // layers 1..3 (folded transitions)
  unsigned short* gprev = g0;
  unsigned short* gnext = g1;
  for (int l = 1; l < N_LAYERS; ++l) {
    gemm_qn<256><<<1250, 256, 0, stream>>>(
        gprev, W2buf + (size_t)(l - 1) * 32768, bias2 + (size_t)(l - 1) * 256, hq);
    edge_fused<8, 8><<<N_NODES / 2, 128, 0, stream>>>(hq + 128, hq, src, row_start, gnext);
    unsigned short* tmp = gprev; gprev = gnext; gnext = tmp;
  }
  // head folded with Wv_3
  out_head_mfma<<<625, 256, 0, stream>>>(gprev, wout2, bout2, out);
}